// Round 1
// baseline (2095.051 us; speedup 1.0000x reference)
//
#include <hip/hip_runtime.h>

typedef unsigned short u16;
typedef unsigned int u32;
typedef unsigned long long u64;
typedef __attribute__((ext_vector_type(8))) short bf16x8;
typedef __attribute__((ext_vector_type(4))) float f32x4;

#define B2 2
#define T2 2048
#define D2 1024
#define H2 8
#define DH 128
#define KSL 512
#define CH 128
#define NCH 16
#define NBH 16
#define MAGIC 0x13579BDFu

__device__ __forceinline__ float bf2f(u32 h) { union { u32 u; float f; } x; x.u = h << 16; return x.f; }
__device__ __forceinline__ u16 f2bf(float f) {
  union { float f; u32 u; } x; x.f = f;
  return (u16)((x.u + 0x7FFFu + ((x.u >> 16) & 1u)) >> 16);
}
__device__ __forceinline__ u32 pack2(float a, float b) { return (u32)f2bf(a) | ((u32)f2bf(b) << 16); }

// ---------------------------------------------------------------------------
// Kernel 1: fused QKV projection.  C[m,n] = x[m,:]·W[n,:] + b[n], M=4096,
// N=3072, K=1024.  bf16 MFMA 16x16x32, 128x128 tile, BK=64, 4 waves (2x2).
// Epilogue scatters into head-major bf16 buffers qh/kh/vh [bh][t][dh].
// ---------------------------------------------------------------------------
__global__ __launch_bounds__(256) void qkv_gemm(
    const float* __restrict__ x, const float* __restrict__ w,
    const float* __restrict__ bias, u16* __restrict__ qhb,
    u16* __restrict__ khb, u16* __restrict__ vhb) {
  __shared__ u16 As[128 * 72];
  __shared__ u16 Bs[128 * 72];
  const int tid = threadIdx.x;
  const int lane = tid & 63, wv = tid >> 6;
  const int quad = lane >> 4, l15 = lane & 15;
  const int m0 = blockIdx.y * 128, n0 = blockIdx.x * 128;
  const int wr = wv >> 1, wc = wv & 1;
  f32x4 acc[4][4];
#pragma unroll
  for (int i = 0; i < 4; ++i)
#pragma unroll
    for (int j = 0; j < 4; ++j) acc[i][j] = f32x4{0.f, 0.f, 0.f, 0.f};
  const int f4c = tid & 15, r0 = tid >> 4;
  for (int kt = 0; kt < 16; ++kt) {
#pragma unroll
    for (int i = 0; i < 8; ++i) {
      int row = r0 + i * 16;
      float4 a = *(const float4*)(x + (size_t)(m0 + row) * 1024 + kt * 64 + f4c * 4);
      float4 b = *(const float4*)(w + (size_t)(n0 + row) * 1024 + kt * 64 + f4c * 4);
      *(uint2*)(&As[row * 72 + f4c * 4]) = make_uint2(pack2(a.x, a.y), pack2(a.z, a.w));
      *(uint2*)(&Bs[row * 72 + f4c * 4]) = make_uint2(pack2(b.x, b.y), pack2(b.z, b.w));
    }
    __syncthreads();
#pragma unroll
    for (int ks = 0; ks < 2; ++ks) {
      bf16x8 af[4], bff[4];
#pragma unroll
      for (int rt = 0; rt < 4; ++rt)
        af[rt] = *(const bf16x8*)(&As[(wr * 64 + rt * 16 + l15) * 72 + ks * 32 + quad * 8]);
#pragma unroll
      for (int ct = 0; ct < 4; ++ct)
        bff[ct] = *(const bf16x8*)(&Bs[(wc * 64 + ct * 16 + l15) * 72 + ks * 32 + quad * 8]);
#pragma unroll
      for (int rt = 0; rt < 4; ++rt)
#pragma unroll
        for (int ct = 0; ct < 4; ++ct)
          acc[rt][ct] = __builtin_amdgcn_mfma_f32_16x16x32_bf16(af[rt], bff[ct], acc[rt][ct], 0, 0, 0);
    }
    __syncthreads();
  }
#pragma unroll
  for (int ct = 0; ct < 4; ++ct) {
    int n = n0 + wc * 64 + ct * 16 + l15;
    float bv = bias[n];
    int sec = n >> 10, rr2 = n & 1023, hh = rr2 >> 7, dd = rr2 & 127;
    u16* dst = (sec == 0) ? qhb : (sec == 1) ? khb : vhb;
#pragma unroll
    for (int rt = 0; rt < 4; ++rt)
#pragma unroll
      for (int rg = 0; rg < 4; ++rg) {
        int m = m0 + wr * 64 + rt * 16 + quad * 4 + rg;
        int bb = m >> 11, tt = m & 2047;
        dst[((size_t)(bb * 8 + hh) * T2 + tt) * DH + dd] = f2bf(acc[rt][ct][rg] + bv);
      }
  }
}

// ---------------------------------------------------------------------------
// Kernel 2: sliding-window (512) block-causal attention, flash-style.
// One block per (bh, 128-row q tile); kv tiles of 64.  Writes y_in (stores).
// ---------------------------------------------------------------------------
__global__ __launch_bounds__(256) void attn_kernel(
    const u16* __restrict__ qhb, const u16* __restrict__ khb,
    const u16* __restrict__ vhb, float* __restrict__ yin) {
  __shared__ u16 Pls[128 * 72];
  __shared__ u16 VT[128 * 72];
  const int tid = threadIdx.x;
  const int lane = tid & 63, wv = tid >> 6;
  const int quad = lane >> 4, l15 = lane & 15;
  const int bh = blockIdx.y, qt = blockIdx.x;
  const int t0 = qt * 128;
  const int b = bh >> 3, h = bh & 7;
  f32x4 Oa[2][8];
  float mrow[2][4], lrow[2][4];
#pragma unroll
  for (int rt = 0; rt < 2; ++rt) {
#pragma unroll
    for (int dt = 0; dt < 8; ++dt) Oa[rt][dt] = f32x4{0.f, 0.f, 0.f, 0.f};
#pragma unroll
    for (int rg = 0; rg < 4; ++rg) { mrow[rt][rg] = -1e30f; lrow[rt][rg] = 0.f; }
  }
  const u16* qbase = qhb + ((size_t)bh * T2 + t0) * DH;
  int j0 = t0 / 64 - 8; if (j0 < 0) j0 = 0;
  int j1 = t0 / 64 + 1;
  for (int jt = j0; jt <= j1; ++jt) {
    int kv0 = jt * 64;
    __syncthreads();
    {  // stage V transposed: VT[d][kv]
      int r = tid & 63, dq = tid >> 6;
      const u16* vrow = vhb + ((size_t)bh * T2 + kv0 + r) * DH + dq * 32;
#pragma unroll
      for (int u = 0; u < 4; ++u) {
        uint4 pv = *(const uint4*)(vrow + u * 8);
        int d0 = dq * 32 + u * 8;
        VT[(d0 + 0) * 72 + r] = (u16)(pv.x); VT[(d0 + 1) * 72 + r] = (u16)(pv.x >> 16);
        VT[(d0 + 2) * 72 + r] = (u16)(pv.y); VT[(d0 + 3) * 72 + r] = (u16)(pv.y >> 16);
        VT[(d0 + 4) * 72 + r] = (u16)(pv.z); VT[(d0 + 5) * 72 + r] = (u16)(pv.z >> 16);
        VT[(d0 + 6) * 72 + r] = (u16)(pv.w); VT[(d0 + 7) * 72 + r] = (u16)(pv.w >> 16);
      }
    }
    f32x4 Sa[2][4];
#pragma unroll
    for (int rt = 0; rt < 2; ++rt)
#pragma unroll
      for (int ct = 0; ct < 4; ++ct) Sa[rt][ct] = f32x4{0.f, 0.f, 0.f, 0.f};
#pragma unroll
    for (int ks = 0; ks < 4; ++ks) {
      bf16x8 a0 = *(const bf16x8*)(qbase + (size_t)(wv * 32 + l15) * DH + ks * 32 + quad * 8);
      bf16x8 a1 = *(const bf16x8*)(qbase + (size_t)(wv * 32 + 16 + l15) * DH + ks * 32 + quad * 8);
#pragma unroll
      for (int ct = 0; ct < 4; ++ct) {
        bf16x8 bb = *(const bf16x8*)(khb + ((size_t)bh * T2 + kv0 + ct * 16 + l15) * DH + ks * 32 + quad * 8);
        Sa[0][ct] = __builtin_amdgcn_mfma_f32_16x16x32_bf16(a0, bb, Sa[0][ct], 0, 0, 0);
        Sa[1][ct] = __builtin_amdgcn_mfma_f32_16x16x32_bf16(a1, bb, Sa[1][ct], 0, 0, 0);
      }
    }
#pragma unroll
    for (int rt = 0; rt < 2; ++rt)
#pragma unroll
      for (int rg = 0; rg < 4; ++rg) {
        int row = wv * 32 + rt * 16 + quad * 4 + rg;
        int qp = t0 + row;
        float vals[4];
        float mx = -1e30f;
#pragma unroll
        for (int ct = 0; ct < 4; ++ct) {
          int kp = kv0 + ct * 16 + l15;
          float s = Sa[rt][ct][rg] * 0.08838834764831845f;
          bool ok = (kp <= qp) && (kp + 512 > qp);
          s = ok ? s : -1e30f;
          vals[ct] = s;
          mx = fmaxf(mx, s);
        }
#pragma unroll
        for (int sh = 1; sh < 16; sh <<= 1) mx = fmaxf(mx, __shfl_xor(mx, sh));
        float mold = mrow[rt][rg];
        float mnew = fmaxf(mold, mx);
        float alpha = __expf(mold - mnew);
        float rsum = 0.f;
        float pv_[4];
#pragma unroll
        for (int ct = 0; ct < 4; ++ct) {
          float p = (vals[ct] < -1e29f) ? 0.f : __expf(vals[ct] - mnew);
          pv_[ct] = p; rsum += p;
        }
#pragma unroll
        for (int sh = 1; sh < 16; sh <<= 1) rsum += __shfl_xor(rsum, sh);
        lrow[rt][rg] = lrow[rt][rg] * alpha + rsum;
        mrow[rt][rg] = mnew;
#pragma unroll
        for (int dt = 0; dt < 8; ++dt) Oa[rt][dt][rg] *= alpha;
#pragma unroll
        for (int ct = 0; ct < 4; ++ct) Pls[row * 72 + ct * 16 + l15] = f2bf(pv_[ct]);
      }
    __syncthreads();
#pragma unroll
    for (int ks = 0; ks < 2; ++ks) {
      bf16x8 a0 = *(const bf16x8*)(&Pls[(wv * 32 + l15) * 72 + ks * 32 + quad * 8]);
      bf16x8 a1 = *(const bf16x8*)(&Pls[(wv * 32 + 16 + l15) * 72 + ks * 32 + quad * 8]);
#pragma unroll
      for (int dt = 0; dt < 8; ++dt) {
        bf16x8 bb = *(const bf16x8*)(&VT[(dt * 16 + l15) * 72 + ks * 32 + quad * 8]);
        Oa[0][dt] = __builtin_amdgcn_mfma_f32_16x16x32_bf16(a0, bb, Oa[0][dt], 0, 0, 0);
        Oa[1][dt] = __builtin_amdgcn_mfma_f32_16x16x32_bf16(a1, bb, Oa[1][dt], 0, 0, 0);
      }
    }
  }
#pragma unroll
  for (int rt = 0; rt < 2; ++rt)
#pragma unroll
    for (int rg = 0; rg < 4; ++rg) {
      int row = wv * 32 + rt * 16 + quad * 4 + rg;
      float invl = 1.0f / lrow[rt][rg];
#pragma unroll
      for (int dt = 0; dt < 8; ++dt)
        yin[((size_t)b * T2 + t0 + row) * D2 + h * DH + dt * 16 + l15] = Oa[rt][dt][rg] * invl;
    }
}

// ---------------------------------------------------------------------------
// Kernel 3: the sequential slot-memory scan.  8 blocks per bh (128 blocks),
// per-bh device-scope barrier between phases.  Owner-pull update scheme.
// ---------------------------------------------------------------------------
struct ScanArgs {
  const u16* qhb; const u16* khb; const u16* vhb;
  float* yin; float* sk; float* sv; u16* skb; u16* khatb;
  u32* cnt; uint4* entries; u32* ocnt; uint4* oflow;
  u32* barcnt; u32* bargen; u32* ready;
  const float* sinit; const float* temp;
};

__device__ void bh_barrier(u32* cnt, u32* gen) {
  __syncthreads();
  if (threadIdx.x == 0) {
    __threadfence();
    u32 g = __hip_atomic_load(gen, __ATOMIC_RELAXED, __HIP_MEMORY_SCOPE_AGENT);
    u32 a = __hip_atomic_fetch_add(cnt, 1u, __ATOMIC_ACQ_REL, __HIP_MEMORY_SCOPE_AGENT);
    if (a == 7u) {
      __hip_atomic_store(cnt, 0u, __ATOMIC_RELAXED, __HIP_MEMORY_SCOPE_AGENT);
      __hip_atomic_store(gen, g + 1u, __ATOMIC_RELEASE, __HIP_MEMORY_SCOPE_AGENT);
    } else {
      while (__hip_atomic_load(gen, __ATOMIC_ACQUIRE, __HIP_MEMORY_SCOPE_AGENT) == g)
        __builtin_amdgcn_s_sleep(2);
    }
    __threadfence();
  }
  __syncthreads();
}

// Exact top-16-of-512 for one row, whole wave, uniform (no wave divergence in
// the hot path).  Lane-max bitonic sort gives threshold t <= v16; ballot-
// compacted survivors (>=16, typically ~25) sorted by (value, ~idx) 64-bit key
// reproduces jax.lax.top_k ordering.  Results land in lanes 48..63 (lane 63 =
// rank 0); p_out = softmax over the 16 values.
__device__ __forceinline__ void topk16(const float* rowp, int lane, volatile u64* candw,
                                       float& p_out, u32& idx_out) {
  u32 mono[8];
#pragma unroll
  for (int j = 0; j < 8; ++j) {
    float f = rowp[j * 64 + lane];
    u32 u = __float_as_uint(f);
    mono[j] = ((int)u < 0) ? ~u : (u | 0x80000000u);
  }
  u32 mx = mono[0];
#pragma unroll
  for (int j = 1; j < 8; ++j) mx = max(mx, mono[j]);
  u32 s = mx;
#pragma unroll
  for (int k = 2; k <= 64; k <<= 1) {
#pragma unroll
    for (int j = k >> 1; j > 0; j >>= 1) {
      u32 o = (u32)__shfl_xor((int)s, j);
      bool keep_min = (((lane & k) == 0) == ((lane & j) == 0));
      u32 mn = min(s, o), mxx = max(s, o);
      s = keep_min ? mn : mxx;
    }
  }
  u32 thr = (u32)__shfl((int)s, 48);
  u32 base = 0;
#pragma unroll
  for (int j = 0; j < 8; ++j) {
    bool pred = (mono[j] >= thr);
    u64 mask = __ballot(pred);
    u32 pos = base + (u32)__popcll(mask & ((1ull << lane) - 1ull));
    if (pred && pos < 64u)
      candw[pos] = (((u64)mono[j]) << 32) | (u64)(0xFFFFFFFFu - (u32)(j * 64 + lane));
    base += (u32)__popcll(mask);
  }
  __threadfence_block();
  u32 cntc = base < 64u ? base : 64u;
  u64 key = ((u32)lane < cntc) ? candw[lane] : 0ull;
#pragma unroll
  for (int k = 2; k <= 64; k <<= 1) {
#pragma unroll
    for (int j = k >> 1; j > 0; j >>= 1) {
      u64 o = __shfl_xor(key, j);
      bool keep_min = (((lane & k) == 0) == ((lane & j) == 0));
      u64 mn = key < o ? key : o;
      u64 mxx = key < o ? o : key;
      key = keep_min ? mn : mxx;
    }
  }
  u32 um = (u32)(key >> 32);
  float val = __uint_as_float((um & 0x80000000u) ? (um & 0x7FFFFFFFu) : ~um);
  idx_out = 0xFFFFFFFFu - (u32)(key & 0xFFFFFFFFull);
  float mtop = __shfl(val, 63);
  float e = __expf(val - mtop);
  float ssum = e;
#pragma unroll
  for (int sh = 1; sh < 16; sh <<= 1) ssum += __shfl_xor(ssum, sh);
  p_out = e / ssum;
}

__global__ __launch_bounds__(512, 2) void scan_kernel(ScanArgs A) {
  const int tid = threadIdx.x;
  const int lane = tid & 63, wv = tid >> 6;
  const int quad = lane >> 4, l15 = lane & 15;
  const int bh = blockIdx.x >> 3, blk = blockIdx.x & 7;
  const int b = bh >> 3, h = bh & 7;
  __shared__ u16 khat_ls[16 * 136];
  __shared__ float scores_ls[16 * 520];
  __shared__ u64 cand[8][64];

  const float invtemp = 1.0f / A.temp[0];
  const float sc_r = 0.08838834764831845f * invtemp;

  // ---- init: slot state (rows blk*64..+64), counters, barrier vars ----
#pragma unroll 1
  for (int i = 0; i < 8; ++i) {
    int s = blk * 64 + wv * 8 + i;
    float2 v2 = *(const float2*)(A.sinit + (size_t)s * 1024 + h * 128 + lane * 2);
    float ssq = v2.x * v2.x + v2.y * v2.y;
#pragma unroll
    for (int sh = 1; sh < 64; sh <<= 1) ssq += __shfl_xor(ssq, sh);
    float inv = 1.0f / (sqrtf(ssq) + 1e-6f);
    size_t off = ((size_t)bh * KSL + s) * DH + lane * 2;
    *(float2*)(A.sk + off) = make_float2(v2.x * inv, v2.y * inv);
    *(float2*)(A.sv + off) = v2;
    *(u32*)(A.skb + off) = pack2(v2.x * inv, v2.y * inv);
    if (lane == 0) A.cnt[bh * KSL + s] = 0u;
  }
  if (blk == 0 && tid == 0) { A.ocnt[bh] = 0u; A.barcnt[bh] = 0u; A.bargen[bh] = 0u; }
  __syncthreads();
  if (tid == 0) {  // ready-flag gate (works on 0xAA-poisoned memory)
    __threadfence();
    __hip_atomic_store(&A.ready[bh * 8 + blk], MAGIC, __ATOMIC_RELEASE, __HIP_MEMORY_SCOPE_AGENT);
    for (int i = 0; i < 8; ++i)
      while (__hip_atomic_load(&A.ready[bh * 8 + i], __ATOMIC_ACQUIRE, __HIP_MEMORY_SCOPE_AGENT) != MAGIC)
        __builtin_amdgcn_s_sleep(2);
    __threadfence();
  }
  __syncthreads();

  u32* bcnt = A.barcnt + bh;
  u32* bgen = A.bargen + bh;

#pragma unroll 1
  for (int ci = 0; ci < NCH; ++ci) {
    const int t0 = ci * CH + blk * 16;
    // ---- A0: k-hat (l2norm of this block's 16 k rows) ----
#pragma unroll 1
    for (int rr = 0; rr < 2; ++rr) {
      int lr = wv * 2 + rr;
      u32 kraw = *(const u32*)(A.khb + ((size_t)bh * T2 + t0 + lr) * DH + lane * 2);
      float k0 = bf2f(kraw & 0xFFFFu), k1 = bf2f(kraw >> 16);
      float ssq = k0 * k0 + k1 * k1;
#pragma unroll
      for (int sh = 1; sh < 64; sh <<= 1) ssq += __shfl_xor(ssq, sh);
      float inv = 1.0f / (sqrtf(ssq) + 1e-6f);
      u32 pk = pack2(k0 * inv, k1 * inv);
      *(u32*)(&khat_ls[lr * 136 + lane * 2]) = pk;
      *(u32*)(A.khatb + ((size_t)bh * CH + blk * 16 + lr) * DH + lane * 2) = pk;
    }
    __syncthreads();
    // ---- A1: read scores = q · slot_k^T * scale / temp ----
    {
      const u16* qbase = A.qhb + ((size_t)bh * T2 + t0) * DH;
      const u16* sbase = A.skb + (size_t)bh * KSL * DH;
      f32x4 acc[4];
#pragma unroll
      for (int ct = 0; ct < 4; ++ct) acc[ct] = f32x4{0.f, 0.f, 0.f, 0.f};
#pragma unroll
      for (int ks = 0; ks < 4; ++ks) {
        bf16x8 a = *(const bf16x8*)(qbase + (size_t)l15 * DH + ks * 32 + quad * 8);
#pragma unroll
        for (int ct = 0; ct < 4; ++ct) {
          bf16x8 bb = *(const bf16x8*)(sbase + (size_t)(wv * 64 + ct * 16 + l15) * DH + ks * 32 + quad * 8);
          acc[ct] = __builtin_amdgcn_mfma_f32_16x16x32_bf16(a, bb, acc[ct], 0, 0, 0);
        }
      }
#pragma unroll
      for (int ct = 0; ct < 4; ++ct)
#pragma unroll
        for (int rg = 0; rg < 4; ++rg)
          scores_ls[(quad * 4 + rg) * 520 + wv * 64 + ct * 16 + l15] = acc[ct][rg] * sc_r;
    }
    __syncthreads();
    // ---- A2: top-16 read + gather slot_v, add into y_in ----
#pragma unroll 1
    for (int rr = 0; rr < 2; ++rr) {
      int lr = wv * 2 + rr;
      float p; u32 sidx;
      topk16(&scores_ls[lr * 520], lane, cand[wv], p, sidx);
      float acc0 = 0.f, acc1 = 0.f;
      const float* svb = A.sv + (size_t)bh * KSL * DH;
#pragma unroll
      for (int r = 0; r < 16; ++r) {
        float pr = __shfl(p, 63 - r);
        u32 ir = (u32)__shfl((int)sidx, 63 - r);
        float2 vv = *(const float2*)(svb + (size_t)ir * DH + lane * 2);
        acc0 += pr * vv.x; acc1 += pr * vv.y;
      }
      float* yp = A.yin + ((size_t)b * T2 + t0 + lr) * D2 + h * DH + lane * 2;
      yp[0] += acc0; yp[1] += acc1;
    }
    __syncthreads();
    // ---- A3: write scores = k_hat · slot_k^T (no scale) ----
    {
      const u16* sbase = A.skb + (size_t)bh * KSL * DH;
      f32x4 acc[4];
#pragma unroll
      for (int ct = 0; ct < 4; ++ct) acc[ct] = f32x4{0.f, 0.f, 0.f, 0.f};
#pragma unroll
      for (int ks = 0; ks < 4; ++ks) {
        bf16x8 a = *(const bf16x8*)(&khat_ls[l15 * 136 + ks * 32 + quad * 8]);
#pragma unroll
        for (int ct = 0; ct < 4; ++ct) {
          bf16x8 bb = *(const bf16x8*)(sbase + (size_t)(wv * 64 + ct * 16 + l15) * DH + ks * 32 + quad * 8);
          acc[ct] = __builtin_amdgcn_mfma_f32_16x16x32_bf16(a, bb, acc[ct], 0, 0, 0);
        }
      }
#pragma unroll
      for (int ct = 0; ct < 4; ++ct)
#pragma unroll
        for (int rg = 0; rg < 4; ++rg)
          scores_ls[(quad * 4 + rg) * 520 + wv * 64 + ct * 16 + l15] = acc[ct][rg];
    }
    __syncthreads();
    // ---- A4: top-16 write; proj = v·sel_k; append entry to slot list ----
#pragma unroll 1
    for (int rr = 0; rr < 2; ++rr) {
      int lr = wv * 2 + rr;
      int c = blk * 16 + lr;
      float wp; u32 widx;
      topk16(&scores_ls[lr * 520], lane, cand[wv], wp, widx);
      u32 vraw = *(const u32*)(A.vhb + ((size_t)bh * T2 + t0 + lr) * DH + lane * 2);
      float vt0 = bf2f(vraw & 0xFFFFu), vt1 = bf2f(vraw >> 16);
      const float* skf = A.sk + (size_t)bh * KSL * DH;
#pragma unroll 1
      for (int r = 0; r < 16; ++r) {
        float wr = __shfl(wp, 63 - r);
        u32 ir = (u32)__shfl((int)widx, 63 - r);
        float2 kk = *(const float2*)(skf + (size_t)ir * DH + lane * 2);
        float part = vt0 * kk.x + vt1 * kk.y;
#pragma unroll
        for (int sh = 1; sh < 64; sh <<= 1) part += __shfl_xor(part, sh);
        if (lane == 0) {
          u32 pos = atomicAdd(&A.cnt[bh * KSL + ir], 1u);
          if (pos < 32u) {
            A.entries[((size_t)bh * KSL + ir) * 32 + pos] =
                make_uint4((u32)c, __float_as_uint(wr), __float_as_uint(part), 0u);
          } else {
            u32 op = atomicAdd(&A.ocnt[bh], 1u);
            A.oflow[(size_t)bh * 32768 + op] =
                make_uint4(((u32)ci << 16) | ir, (u32)c, __float_as_uint(wr), __float_as_uint(part));
          }
        }
      }
    }
    bh_barrier(bcnt, bgen);
    // ---- B: each slot row pulls its updates; decay, add, renorm ----
#pragma unroll 1
    for (int i = 0; i < 8; ++i) {
      int s = blk * 64 + wv * 8 + i;
      size_t roff = ((size_t)bh * KSL + s) * DH + lane * 2;
      u32 n = A.cnt[bh * KSL + s];
      float2 V = *(const float2*)(A.sv + roff);
      float2 Kr = *(const float2*)(A.sk + roff);
      float dv0 = 0, dv1 = 0, dk0 = 0, dk1 = 0;
      u32 nd = n < 32u ? n : 32u;
#pragma unroll 1
      for (u32 e = 0; e < nd; ++e) {
        uint4 ent = A.entries[((size_t)bh * KSL + s) * 32 + e];
        u32 c2 = ent.x; float wpe = __uint_as_float(ent.y), pj = __uint_as_float(ent.z);
        u32 vr = *(const u32*)(A.vhb + ((size_t)bh * T2 + ci * CH + c2) * DH + lane * 2);
        u32 hr = *(const u32*)(A.khatb + ((size_t)bh * CH + c2) * DH + lane * 2);
        dv0 += wpe * (bf2f(vr & 0xFFFFu) - pj * Kr.x);
        dv1 += wpe * (bf2f(vr >> 16) - pj * Kr.y);
        dk0 += wpe * (bf2f(hr & 0xFFFFu) - Kr.x);
        dk1 += wpe * (bf2f(hr >> 16) - Kr.y);
      }
      if (n > 32u) {  // rare overflow path (correctness safety net)
        u32 oc = A.ocnt[bh];
        u32 tag = ((u32)ci << 16) | (u32)s;
#pragma unroll 1
        for (u32 e = 0; e < oc; ++e) {
          uint4 ent = A.oflow[(size_t)bh * 32768 + e];
          if (ent.x == tag) {
            u32 c2 = ent.y; float wpe = __uint_as_float(ent.z), pj = __uint_as_float(ent.w);
            u32 vr = *(const u32*)(A.vhb + ((size_t)bh * T2 + ci * CH + c2) * DH + lane * 2);
            u32 hr = *(const u32*)(A.khatb + ((size_t)bh * CH + c2) * DH + lane * 2);
            dv0 += wpe * (bf2f(vr & 0xFFFFu) - pj * Kr.x);
            dv1 += wpe * (bf2f(vr >> 16) - pj * Kr.y);
            dk0 += wpe * (bf2f(hr & 0xFFFFu) - Kr.x);
            dk1 += wpe * (bf2f(hr >> 16) - Kr.y);
          }
        }
      }
      *(float2*)(A.sv + roff) = make_float2(0.99f * V.x + 0.1f * dv0, 0.99f * V.y + 0.1f * dv1);
      if (n > 0u) {
        float u0 = Kr.x + 0.1f * dk0, u1 = Kr.y + 0.1f * dk1;
        float ssq = u0 * u0 + u1 * u1;
#pragma unroll
        for (int sh = 1; sh < 64; sh <<= 1) ssq += __shfl_xor(ssq, sh);
        float inv = 1.0f / (sqrtf(ssq) + 1e-6f);
        u0 *= inv; u1 *= inv;
        *(float2*)(A.sk + roff) = make_float2(u0, u1);
        *(u32*)(A.skb + roff) = pack2(u0, u1);
      }
      if (lane == 0) A.cnt[bh * KSL + s] = 0u;
    }
    bh_barrier(bcnt, bgen);
  }
}

// ---------------------------------------------------------------------------
// Kernel 4: output projection.  out = y_in · W_o^T + b_o, M=4096, N=K=1024.
// ---------------------------------------------------------------------------
__global__ __launch_bounds__(256) void out_gemm(
    const float* __restrict__ yin, const float* __restrict__ w,
    const float* __restrict__ bias, float* __restrict__ out) {
  __shared__ u16 As[128 * 72];
  __shared__ u16 Bs[128 * 72];
  const int tid = threadIdx.x;
  const int lane = tid & 63, wv = tid >> 6;
  const int quad = lane >> 4, l15 = lane & 15;
  const int m0 = blockIdx.y * 128, n0 = blockIdx.x * 128;
  const int wr = wv >> 1, wc = wv & 1;
  f32x4 acc[4][4];
#pragma unroll
  for (int i = 0; i < 4; ++i)
#pragma unroll
    for (int j = 0; j < 4; ++j) acc[i][j] = f32x4{0.f, 0.f, 0.f, 0.f};
  const int f4c = tid & 15, r0 = tid >> 4;
  for (int kt = 0; kt < 16; ++kt) {
#pragma unroll
    for (int i = 0; i < 8; ++i) {
      int row = r0 + i * 16;
      float4 a = *(const float4*)(yin + (size_t)(m0 + row) * 1024 + kt * 64 + f4c * 4);
      float4 b = *(const float4*)(w + (size_t)(n0 + row) * 1024 + kt * 64 + f4c * 4);
      *(uint2*)(&As[row * 72 + f4c * 4]) = make_uint2(pack2(a.x, a.y), pack2(a.z, a.w));
      *(uint2*)(&Bs[row * 72 + f4c * 4]) = make_uint2(pack2(b.x, b.y), pack2(b.z, b.w));
    }
    __syncthreads();
#pragma unroll
    for (int ks = 0; ks < 2; ++ks) {
      bf16x8 af[4], bff[4];
#pragma unroll
      for (int rt = 0; rt < 4; ++rt)
        af[rt] = *(const bf16x8*)(&As[(wr * 64 + rt * 16 + l15) * 72 + ks * 32 + quad * 8]);
#pragma unroll
      for (int ct = 0; ct < 4; ++ct)
        bff[ct] = *(const bf16x8*)(&Bs[(wc * 64 + ct * 16 + l15) * 72 + ks * 32 + quad * 8]);
#pragma unroll
      for (int rt = 0; rt < 4; ++rt)
#pragma unroll
        for (int ct = 0; ct < 4; ++ct)
          acc[rt][ct] = __builtin_amdgcn_mfma_f32_16x16x32_bf16(af[rt], bff[ct], acc[rt][ct], 0, 0, 0);
    }
    __syncthreads();
  }
#pragma unroll
  for (int ct = 0; ct < 4; ++ct) {
    int n = n0 + wc * 64 + ct * 16 + l15;
    float bv = bias[n];
#pragma unroll
    for (int rt = 0; rt < 4; ++rt)
#pragma unroll
      for (int rg = 0; rg < 4; ++rg) {
        int m = m0 + wr * 64 + rt * 16 + quad * 4 + rg;
        out[(size_t)m * 1024 + n] = acc[rt][ct][rg] + bv;
      }
  }
}

// ---------------------------------------------------------------------------
extern "C" void kernel_launch(void* const* d_in, const int* in_sizes, int n_in,
                              void* d_out, int out_size, void* d_ws, size_t ws_size,
                              hipStream_t stream) {
  const float* x = (const float*)d_in[0];
  const float* Wqkv = (const float*)d_in[1];
  const float* bqkv = (const float*)d_in[2];
  const float* Wo = (const float*)d_in[3];
  const float* bo = (const float*)d_in[4];
  const float* Sinit = (const float*)d_in[5];
  const float* temp = (const float*)d_in[6];
  float* out = (float*)d_out;

  char* p = (char*)d_ws;
  auto take = [&](size_t bytes) { char* r = p; p += (bytes + 255) & ~(size_t)255; return r; };
  u16* qhb = (u16*)take((size_t)NBH * T2 * DH * 2);
  u16* khb = (u16*)take((size_t)NBH * T2 * DH * 2);
  u16* vhb = (u16*)take((size_t)NBH * T2 * DH * 2);
  float* yin = (float*)take((size_t)B2 * T2 * D2 * 4);
  float* sk = (float*)take((size_t)NBH * KSL * DH * 4);
  float* sv = (float*)take((size_t)NBH * KSL * DH * 4);
  u16* skb = (u16*)take((size_t)NBH * KSL * DH * 2);
  u16* khatb = (u16*)take((size_t)NBH * CH * DH * 2);
  u32* cnt = (u32*)take((size_t)NBH * KSL * 4);
  uint4* entries = (uint4*)take((size_t)NBH * KSL * 32 * 16);
  u32* ocnt = (u32*)take(64 * 4);
  uint4* oflow = (uint4*)take((size_t)NBH * 32768 * 16);
  u32* barcnt = (u32*)take(64 * 4);
  u32* bargen = (u32*)take(64 * 4);
  u32* ready = (u32*)take(NBH * 8 * 4);

  hipLaunchKernelGGL(qkv_gemm, dim3(24, 32), dim3(256), 0, stream, x, Wqkv, bqkv, qhb, khb, vhb);
  hipLaunchKernelGGL(attn_kernel, dim3(16, 16), dim3(256), 0, stream, qhb, khb, vhb, yin);
  ScanArgs sa{qhb, khb, vhb, yin, sk, sv, skb, khatb, cnt, entries, ocnt, oflow, barcnt, bargen, ready, Sinit, temp};
  hipLaunchKernelGGL(scan_kernel, dim3(128), dim3(512), 0, stream, sa);
  hipLaunchKernelGGL(out_gemm, dim3(8, 32), dim3(256), 0, stream, yin, Wo, bo, out);
}

// Round 2
// 1980.130 us; speedup vs baseline: 1.0580x; 1.0580x over previous
//
#include <hip/hip_runtime.h>

typedef unsigned short u16;
typedef unsigned int u32;
typedef unsigned long long u64;
typedef __attribute__((ext_vector_type(8))) short bf16x8;
typedef __attribute__((ext_vector_type(4))) float f32x4;

#define B2 2
#define T2 2048
#define D2 1024
#define H2 8
#define DH 128
#define KSL 512
#define CH 128
#define NCH 16
#define NBH 16
#define MAGIC 0x13579BDFu

__device__ __forceinline__ float bf2f(u32 h) { union { u32 u; float f; } x; x.u = h << 16; return x.f; }
__device__ __forceinline__ u16 f2bf(float f) {
  union { float f; u32 u; } x; x.f = f;
  return (u16)((x.u + 0x7FFFu + ((x.u >> 16) & 1u)) >> 16);
}
__device__ __forceinline__ u32 pack2(float a, float b) { return (u32)f2bf(a) | ((u32)f2bf(b) << 16); }

// ---------------------------------------------------------------------------
// Kernel 1: fused QKV projection.  (unchanged from R1)
// ---------------------------------------------------------------------------
__global__ __launch_bounds__(256) void qkv_gemm(
    const float* __restrict__ x, const float* __restrict__ w,
    const float* __restrict__ bias, u16* __restrict__ qhb,
    u16* __restrict__ khb, u16* __restrict__ vhb) {
  __shared__ u16 As[128 * 72];
  __shared__ u16 Bs[128 * 72];
  const int tid = threadIdx.x;
  const int lane = tid & 63, wv = tid >> 6;
  const int quad = lane >> 4, l15 = lane & 15;
  const int m0 = blockIdx.y * 128, n0 = blockIdx.x * 128;
  const int wr = wv >> 1, wc = wv & 1;
  f32x4 acc[4][4];
#pragma unroll
  for (int i = 0; i < 4; ++i)
#pragma unroll
    for (int j = 0; j < 4; ++j) acc[i][j] = f32x4{0.f, 0.f, 0.f, 0.f};
  const int f4c = tid & 15, r0 = tid >> 4;
  for (int kt = 0; kt < 16; ++kt) {
#pragma unroll
    for (int i = 0; i < 8; ++i) {
      int row = r0 + i * 16;
      float4 a = *(const float4*)(x + (size_t)(m0 + row) * 1024 + kt * 64 + f4c * 4);
      float4 b = *(const float4*)(w + (size_t)(n0 + row) * 1024 + kt * 64 + f4c * 4);
      *(uint2*)(&As[row * 72 + f4c * 4]) = make_uint2(pack2(a.x, a.y), pack2(a.z, a.w));
      *(uint2*)(&Bs[row * 72 + f4c * 4]) = make_uint2(pack2(b.x, b.y), pack2(b.z, b.w));
    }
    __syncthreads();
#pragma unroll
    for (int ks = 0; ks < 2; ++ks) {
      bf16x8 af[4], bff[4];
#pragma unroll
      for (int rt = 0; rt < 4; ++rt)
        af[rt] = *(const bf16x8*)(&As[(wr * 64 + rt * 16 + l15) * 72 + ks * 32 + quad * 8]);
#pragma unroll
      for (int ct = 0; ct < 4; ++ct)
        bff[ct] = *(const bf16x8*)(&Bs[(wc * 64 + ct * 16 + l15) * 72 + ks * 32 + quad * 8]);
#pragma unroll
      for (int rt = 0; rt < 4; ++rt)
#pragma unroll
        for (int ct = 0; ct < 4; ++ct)
          acc[rt][ct] = __builtin_amdgcn_mfma_f32_16x16x32_bf16(af[rt], bff[ct], acc[rt][ct], 0, 0, 0);
    }
    __syncthreads();
  }
#pragma unroll
  for (int ct = 0; ct < 4; ++ct) {
    int n = n0 + wc * 64 + ct * 16 + l15;
    float bv = bias[n];
    int sec = n >> 10, rr2 = n & 1023, hh = rr2 >> 7, dd = rr2 & 127;
    u16* dst = (sec == 0) ? qhb : (sec == 1) ? khb : vhb;
#pragma unroll
    for (int rt = 0; rt < 4; ++rt)
#pragma unroll
      for (int rg = 0; rg < 4; ++rg) {
        int m = m0 + wr * 64 + rt * 16 + quad * 4 + rg;
        int bb = m >> 11, tt = m & 2047;
        dst[((size_t)(bb * 8 + hh) * T2 + tt) * DH + dd] = f2bf(acc[rt][ct][rg] + bv);
      }
  }
}

// ---------------------------------------------------------------------------
// Kernel 2: sliding-window attention (unchanged from R1)
// ---------------------------------------------------------------------------
__global__ __launch_bounds__(256) void attn_kernel(
    const u16* __restrict__ qhb, const u16* __restrict__ khb,
    const u16* __restrict__ vhb, float* __restrict__ yin) {
  __shared__ u16 Pls[128 * 72];
  __shared__ u16 VT[128 * 72];
  const int tid = threadIdx.x;
  const int lane = tid & 63, wv = tid >> 6;
  const int quad = lane >> 4, l15 = lane & 15;
  const int bh = blockIdx.y, qt = blockIdx.x;
  const int t0 = qt * 128;
  const int b = bh >> 3, h = bh & 7;
  f32x4 Oa[2][8];
  float mrow[2][4], lrow[2][4];
#pragma unroll
  for (int rt = 0; rt < 2; ++rt) {
#pragma unroll
    for (int dt = 0; dt < 8; ++dt) Oa[rt][dt] = f32x4{0.f, 0.f, 0.f, 0.f};
#pragma unroll
    for (int rg = 0; rg < 4; ++rg) { mrow[rt][rg] = -1e30f; lrow[rt][rg] = 0.f; }
  }
  const u16* qbase = qhb + ((size_t)bh * T2 + t0) * DH;
  int j0 = t0 / 64 - 8; if (j0 < 0) j0 = 0;
  int j1 = t0 / 64 + 1;
  for (int jt = j0; jt <= j1; ++jt) {
    int kv0 = jt * 64;
    __syncthreads();
    {
      int r = tid & 63, dq = tid >> 6;
      const u16* vrow = vhb + ((size_t)bh * T2 + kv0 + r) * DH + dq * 32;
#pragma unroll
      for (int u = 0; u < 4; ++u) {
        uint4 pv = *(const uint4*)(vrow + u * 8);
        int d0 = dq * 32 + u * 8;
        VT[(d0 + 0) * 72 + r] = (u16)(pv.x); VT[(d0 + 1) * 72 + r] = (u16)(pv.x >> 16);
        VT[(d0 + 2) * 72 + r] = (u16)(pv.y); VT[(d0 + 3) * 72 + r] = (u16)(pv.y >> 16);
        VT[(d0 + 4) * 72 + r] = (u16)(pv.z); VT[(d0 + 5) * 72 + r] = (u16)(pv.z >> 16);
        VT[(d0 + 6) * 72 + r] = (u16)(pv.w); VT[(d0 + 7) * 72 + r] = (u16)(pv.w >> 16);
      }
    }
    f32x4 Sa[2][4];
#pragma unroll
    for (int rt = 0; rt < 2; ++rt)
#pragma unroll
      for (int ct = 0; ct < 4; ++ct) Sa[rt][ct] = f32x4{0.f, 0.f, 0.f, 0.f};
#pragma unroll
    for (int ks = 0; ks < 4; ++ks) {
      bf16x8 a0 = *(const bf16x8*)(qbase + (size_t)(wv * 32 + l15) * DH + ks * 32 + quad * 8);
      bf16x8 a1 = *(const bf16x8*)(qbase + (size_t)(wv * 32 + 16 + l15) * DH + ks * 32 + quad * 8);
#pragma unroll
      for (int ct = 0; ct < 4; ++ct) {
        bf16x8 bb = *(const bf16x8*)(khb + ((size_t)bh * T2 + kv0 + ct * 16 + l15) * DH + ks * 32 + quad * 8);
        Sa[0][ct] = __builtin_amdgcn_mfma_f32_16x16x32_bf16(a0, bb, Sa[0][ct], 0, 0, 0);
        Sa[1][ct] = __builtin_amdgcn_mfma_f32_16x16x32_bf16(a1, bb, Sa[1][ct], 0, 0, 0);
      }
    }
#pragma unroll
    for (int rt = 0; rt < 2; ++rt)
#pragma unroll
      for (int rg = 0; rg < 4; ++rg) {
        int row = wv * 32 + rt * 16 + quad * 4 + rg;
        int qp = t0 + row;
        float vals[4];
        float mx = -1e30f;
#pragma unroll
        for (int ct = 0; ct < 4; ++ct) {
          int kp = kv0 + ct * 16 + l15;
          float s = Sa[rt][ct][rg] * 0.08838834764831845f;
          bool ok = (kp <= qp) && (kp + 512 > qp);
          s = ok ? s : -1e30f;
          vals[ct] = s;
          mx = fmaxf(mx, s);
        }
#pragma unroll
        for (int sh = 1; sh < 16; sh <<= 1) mx = fmaxf(mx, __shfl_xor(mx, sh));
        float mold = mrow[rt][rg];
        float mnew = fmaxf(mold, mx);
        float alpha = __expf(mold - mnew);
        float rsum = 0.f;
        float pv_[4];
#pragma unroll
        for (int ct = 0; ct < 4; ++ct) {
          float p = (vals[ct] < -1e29f) ? 0.f : __expf(vals[ct] - mnew);
          pv_[ct] = p; rsum += p;
        }
#pragma unroll
        for (int sh = 1; sh < 16; sh <<= 1) rsum += __shfl_xor(rsum, sh);
        lrow[rt][rg] = lrow[rt][rg] * alpha + rsum;
        mrow[rt][rg] = mnew;
#pragma unroll
        for (int dt = 0; dt < 8; ++dt) Oa[rt][dt][rg] *= alpha;
#pragma unroll
        for (int ct = 0; ct < 4; ++ct) Pls[row * 72 + ct * 16 + l15] = f2bf(pv_[ct]);
      }
    __syncthreads();
#pragma unroll
    for (int ks = 0; ks < 2; ++ks) {
      bf16x8 a0 = *(const bf16x8*)(&Pls[(wv * 32 + l15) * 72 + ks * 32 + quad * 8]);
      bf16x8 a1 = *(const bf16x8*)(&Pls[(wv * 32 + 16 + l15) * 72 + ks * 32 + quad * 8]);
#pragma unroll
      for (int dt = 0; dt < 8; ++dt) {
        bf16x8 bb = *(const bf16x8*)(&VT[(dt * 16 + l15) * 72 + ks * 32 + quad * 8]);
        Oa[0][dt] = __builtin_amdgcn_mfma_f32_16x16x32_bf16(a0, bb, Oa[0][dt], 0, 0, 0);
        Oa[1][dt] = __builtin_amdgcn_mfma_f32_16x16x32_bf16(a1, bb, Oa[1][dt], 0, 0, 0);
      }
    }
  }
#pragma unroll
  for (int rt = 0; rt < 2; ++rt)
#pragma unroll
    for (int rg = 0; rg < 4; ++rg) {
      int row = wv * 32 + rt * 16 + quad * 4 + rg;
      float invl = 1.0f / lrow[rt][rg];
#pragma unroll
      for (int dt = 0; dt < 8; ++dt)
        yin[((size_t)b * T2 + t0 + row) * D2 + h * DH + dt * 16 + l15] = Oa[rt][dt][rg] * invl;
    }
}

// ---------------------------------------------------------------------------
// Kernel 3: slot-memory scan v2.  16 blocks per bh (256 blocks, 512 thr).
// Per wave: 1 chunk-row (phase A) and 4 slots (phase B).
// A4: lane-parallel proj (4 lanes/pick) + single wave-wide atomic append.
// Entries capacity = 128/slot (hard max) -> overflow path deleted.
// Phase B: batch-8 entry loads to collapse dependent-load chains.
// ---------------------------------------------------------------------------
struct ScanArgs {
  const u16* qhb; const u16* khb; const u16* vhb;
  float* yin; float* sk; float* sv; u16* skb; u16* khatb;
  u32* cnt; uint4* entries;
  u32* barcnt; u32* bargen; u32* ready;
  const float* sinit; const float* temp;
};

__device__ void bh_barrier(u32* cnt, u32* gen) {
  __syncthreads();
  if (threadIdx.x == 0) {
    __threadfence();
    u32 g = __hip_atomic_load(gen, __ATOMIC_RELAXED, __HIP_MEMORY_SCOPE_AGENT);
    u32 a = __hip_atomic_fetch_add(cnt, 1u, __ATOMIC_ACQ_REL, __HIP_MEMORY_SCOPE_AGENT);
    if (a == 15u) {
      __hip_atomic_store(cnt, 0u, __ATOMIC_RELAXED, __HIP_MEMORY_SCOPE_AGENT);
      __hip_atomic_store(gen, g + 1u, __ATOMIC_RELEASE, __HIP_MEMORY_SCOPE_AGENT);
    } else {
      while (__hip_atomic_load(gen, __ATOMIC_ACQUIRE, __HIP_MEMORY_SCOPE_AGENT) == g)
        __builtin_amdgcn_s_sleep(2);
    }
    __threadfence();
  }
  __syncthreads();
}

__device__ __forceinline__ void topk16(const float* rowp, int lane, volatile u64* candw,
                                       float& p_out, u32& idx_out) {
  u32 mono[8];
#pragma unroll
  for (int j = 0; j < 8; ++j) {
    float f = rowp[j * 64 + lane];
    u32 u = __float_as_uint(f);
    mono[j] = ((int)u < 0) ? ~u : (u | 0x80000000u);
  }
  u32 mx = mono[0];
#pragma unroll
  for (int j = 1; j < 8; ++j) mx = max(mx, mono[j]);
  u32 s = mx;
#pragma unroll
  for (int k = 2; k <= 64; k <<= 1) {
#pragma unroll
    for (int j = k >> 1; j > 0; j >>= 1) {
      u32 o = (u32)__shfl_xor((int)s, j);
      bool keep_min = (((lane & k) == 0) == ((lane & j) == 0));
      u32 mn = min(s, o), mxx = max(s, o);
      s = keep_min ? mn : mxx;
    }
  }
  u32 thr = (u32)__shfl((int)s, 48);
  u32 base = 0;
#pragma unroll
  for (int j = 0; j < 8; ++j) {
    bool pred = (mono[j] >= thr);
    u64 mask = __ballot(pred);
    u32 pos = base + (u32)__popcll(mask & ((1ull << lane) - 1ull));
    if (pred && pos < 64u)
      candw[pos] = (((u64)mono[j]) << 32) | (u64)(0xFFFFFFFFu - (u32)(j * 64 + lane));
    base += (u32)__popcll(mask);
  }
  __threadfence_block();
  u32 cntc = base < 64u ? base : 64u;
  u64 key = ((u32)lane < cntc) ? candw[lane] : 0ull;
#pragma unroll
  for (int k = 2; k <= 64; k <<= 1) {
#pragma unroll
    for (int j = k >> 1; j > 0; j >>= 1) {
      u64 o = __shfl_xor(key, j);
      bool keep_min = (((lane & k) == 0) == ((lane & j) == 0));
      u64 mn = key < o ? key : o;
      u64 mxx = key < o ? o : key;
      key = keep_min ? mn : mxx;
    }
  }
  u32 um = (u32)(key >> 32);
  float val = __uint_as_float((um & 0x80000000u) ? (um & 0x7FFFFFFFu) : ~um);
  idx_out = 0xFFFFFFFFu - (u32)(key & 0xFFFFFFFFull);
  float mtop = __shfl(val, 63);
  float e = __expf(val - mtop);
  float ssum = e;
#pragma unroll
  for (int sh = 1; sh < 16; sh <<= 1) ssum += __shfl_xor(ssum, sh);
  p_out = e / ssum;
}

__global__ __launch_bounds__(512, 2) void scan_kernel(ScanArgs A) {
  const int tid = threadIdx.x;
  const int lane = tid & 63, wv = tid >> 6;
  const int quad = lane >> 4, l15 = lane & 15;
  const int bh = blockIdx.x >> 4, blk = blockIdx.x & 15;
  const int b = bh >> 3, h = bh & 7;
  __shared__ u16 khat_ls[8 * 136];
  __shared__ float scores_ls[8 * 520];
  __shared__ u64 cand[8][64];

  const float invtemp = 1.0f / A.temp[0];
  const float sc_r = 0.08838834764831845f * invtemp;

  // ---- init: this block's 32 slots (4 per wave) ----
#pragma unroll 1
  for (int i = 0; i < 4; ++i) {
    int s = blk * 32 + wv * 4 + i;
    float2 v2 = *(const float2*)(A.sinit + (size_t)s * 1024 + h * 128 + lane * 2);
    float ssq = v2.x * v2.x + v2.y * v2.y;
#pragma unroll
    for (int sh = 1; sh < 64; sh <<= 1) ssq += __shfl_xor(ssq, sh);
    float inv = 1.0f / (sqrtf(ssq) + 1e-6f);
    size_t off = ((size_t)bh * KSL + s) * DH + lane * 2;
    *(float2*)(A.sk + off) = make_float2(v2.x * inv, v2.y * inv);
    *(float2*)(A.sv + off) = v2;
    *(u32*)(A.skb + off) = pack2(v2.x * inv, v2.y * inv);
    if (lane == 0)
      __hip_atomic_store(&A.cnt[bh * KSL + s], 0u, __ATOMIC_RELAXED, __HIP_MEMORY_SCOPE_AGENT);
  }
  if (blk == 0 && tid == 0) { A.barcnt[bh] = 0u; A.bargen[bh] = 0u; }
  __syncthreads();
  if (tid == 0) {  // ready-flag gate (works on 0xAA-poisoned memory)
    __threadfence();
    __hip_atomic_store(&A.ready[bh * 16 + blk], MAGIC, __ATOMIC_RELEASE, __HIP_MEMORY_SCOPE_AGENT);
    for (int i = 0; i < 16; ++i)
      while (__hip_atomic_load(&A.ready[bh * 16 + i], __ATOMIC_ACQUIRE, __HIP_MEMORY_SCOPE_AGENT) != MAGIC)
        __builtin_amdgcn_s_sleep(2);
    __threadfence();
  }
  __syncthreads();

  u32* bcnt = A.barcnt + bh;
  u32* bgen = A.bargen + bh;

#pragma unroll 1
  for (int ci = 0; ci < NCH; ++ci) {
    const int t0base = ci * CH;
    const int c = blk * 8 + wv;          // this wave's chunk-row
    const int trow = t0base + c;
    // ---- A0: k-hat for row c ----
    {
      u32 kraw = *(const u32*)(A.khb + ((size_t)bh * T2 + trow) * DH + lane * 2);
      float k0 = bf2f(kraw & 0xFFFFu), k1 = bf2f(kraw >> 16);
      float ssq = k0 * k0 + k1 * k1;
#pragma unroll
      for (int sh = 1; sh < 64; sh <<= 1) ssq += __shfl_xor(ssq, sh);
      float inv = 1.0f / (sqrtf(ssq) + 1e-6f);
      u32 pk = pack2(k0 * inv, k1 * inv);
      *(u32*)(&khat_ls[wv * 136 + lane * 2]) = pk;
      *(u32*)(A.khatb + ((size_t)bh * CH + c) * DH + lane * 2) = pk;
    }
    __syncthreads();
    // ---- A1: read scores = q · slot_k^T * scale / temp  (8 rows x 512) ----
    {
      const u16* qbase = A.qhb + ((size_t)bh * T2 + t0base + blk * 8) * DH;
      const u16* sbase = A.skb + (size_t)bh * KSL * DH;
      f32x4 acc[4];
#pragma unroll
      for (int ct = 0; ct < 4; ++ct) acc[ct] = f32x4{0.f, 0.f, 0.f, 0.f};
#pragma unroll
      for (int ks = 0; ks < 4; ++ks) {
        bf16x8 a = *(const bf16x8*)(qbase + (size_t)(l15 & 7) * DH + ks * 32 + quad * 8);
#pragma unroll
        for (int ct = 0; ct < 4; ++ct) {
          bf16x8 bb = *(const bf16x8*)(sbase + (size_t)(wv * 64 + ct * 16 + l15) * DH + ks * 32 + quad * 8);
          acc[ct] = __builtin_amdgcn_mfma_f32_16x16x32_bf16(a, bb, acc[ct], 0, 0, 0);
        }
      }
#pragma unroll
      for (int ct = 0; ct < 4; ++ct)
#pragma unroll
        for (int rg = 0; rg < 4; ++rg) {
          int m = quad * 4 + rg;
          if (m < 8) scores_ls[m * 520 + wv * 64 + ct * 16 + l15] = acc[ct][rg] * sc_r;
        }
    }
    __syncthreads();
    // ---- A2: top-16 read + gather slot_v, add into y_in ----
    {
      float p; u32 sidx;
      topk16(&scores_ls[wv * 520], lane, cand[wv], p, sidx);
      float acc0 = 0.f, acc1 = 0.f;
      const float* svb = A.sv + (size_t)bh * KSL * DH;
#pragma unroll
      for (int r = 0; r < 16; ++r) {
        float pr = __shfl(p, 63 - r);
        u32 ir = (u32)__shfl((int)sidx, 63 - r);
        float2 vv = *(const float2*)(svb + (size_t)ir * DH + lane * 2);
        acc0 += pr * vv.x; acc1 += pr * vv.y;
      }
      float* yp = A.yin + ((size_t)b * T2 + trow) * D2 + h * DH + lane * 2;
      yp[0] += acc0; yp[1] += acc1;
    }
    __syncthreads();
    // ---- A3: write scores = k_hat · slot_k^T ----
    {
      const u16* sbase = A.skb + (size_t)bh * KSL * DH;
      f32x4 acc[4];
#pragma unroll
      for (int ct = 0; ct < 4; ++ct) acc[ct] = f32x4{0.f, 0.f, 0.f, 0.f};
#pragma unroll
      for (int ks = 0; ks < 4; ++ks) {
        bf16x8 a = *(const bf16x8*)(&khat_ls[(l15 & 7) * 136 + ks * 32 + quad * 8]);
#pragma unroll
        for (int ct = 0; ct < 4; ++ct) {
          bf16x8 bb = *(const bf16x8*)(sbase + (size_t)(wv * 64 + ct * 16 + l15) * DH + ks * 32 + quad * 8);
          acc[ct] = __builtin_amdgcn_mfma_f32_16x16x32_bf16(a, bb, acc[ct], 0, 0, 0);
        }
      }
#pragma unroll
      for (int ct = 0; ct < 4; ++ct)
#pragma unroll
        for (int rg = 0; rg < 4; ++rg) {
          int m = quad * 4 + rg;
          if (m < 8) scores_ls[m * 520 + wv * 64 + ct * 16 + l15] = acc[ct][rg];
        }
    }
    __syncthreads();
    // ---- A4: top-16 write; lane-parallel proj; wave-wide atomic append ----
    {
      float wp; u32 widx;
      topk16(&scores_ls[wv * 520], lane, cand[wv], wp, widx);
      const int r = lane >> 2, g = lane & 3;   // 16 picks x 4 lanes
      float wr = __shfl(wp, 63 - r);
      u32 ir = (u32)__shfl((int)widx, 63 - r);
      const float* kb = A.sk + ((size_t)bh * KSL + ir) * DH + g * 32;
      const u16* vb = A.vhb + ((size_t)bh * T2 + trow) * DH + g * 32;
      float part = 0.f;
#pragma unroll
      for (int u2 = 0; u2 < 4; ++u2) {
        uint4 vvp = *(const uint4*)(vb + u2 * 8);
        float4 k0 = *(const float4*)(kb + u2 * 8);
        float4 k1 = *(const float4*)(kb + u2 * 8 + 4);
        part += bf2f(vvp.x & 0xFFFFu) * k0.x + bf2f(vvp.x >> 16) * k0.y
              + bf2f(vvp.y & 0xFFFFu) * k0.z + bf2f(vvp.y >> 16) * k0.w
              + bf2f(vvp.z & 0xFFFFu) * k1.x + bf2f(vvp.z >> 16) * k1.y
              + bf2f(vvp.w & 0xFFFFu) * k1.z + bf2f(vvp.w >> 16) * k1.w;
      }
      part += __shfl_xor(part, 1);
      part += __shfl_xor(part, 2);
      if (g == 0) {
        u32 pos = atomicAdd(&A.cnt[bh * KSL + ir], 1u);
        A.entries[((size_t)bh * KSL + ir) * 128 + pos] =
            make_uint4((u32)c, __float_as_uint(wr), __float_as_uint(part), 0u);
      }
    }
    bh_barrier(bcnt, bgen);
    // ---- B: each owned slot pulls its updates (batch-8 entry loads) ----
#pragma unroll 1
    for (int i = 0; i < 4; ++i) {
      int s = blk * 32 + wv * 4 + i;
      size_t slotoff = (size_t)bh * KSL + s;
      size_t roff = slotoff * DH + lane * 2;
      u32 n = __hip_atomic_load(&A.cnt[slotoff], __ATOMIC_RELAXED, __HIP_MEMORY_SCOPE_AGENT);
      float2 V = *(const float2*)(A.sv + roff);
      float2 Kr = *(const float2*)(A.sk + roff);
      float dv0 = 0, dv1 = 0, dk0 = 0, dk1 = 0;
      u32 nd = n < 128u ? n : 128u;
      const uint4* ebase = A.entries + slotoff * 128;
#pragma unroll 1
      for (u32 base2 = 0; base2 < nd; base2 += 8) {
        u32 m = nd - base2; if (m > 8u) m = 8u;
        uint4 eb[8];
#pragma unroll
        for (int j = 0; j < 8; ++j) if (j < (int)m) eb[j] = ebase[base2 + j];
        u32 vr[8], hr[8];
#pragma unroll
        for (int j = 0; j < 8; ++j) if (j < (int)m) {
          u32 c2 = eb[j].x;
          vr[j] = *(const u32*)(A.vhb + ((size_t)bh * T2 + t0base + c2) * DH + lane * 2);
          hr[j] = *(const u32*)(A.khatb + ((size_t)bh * CH + c2) * DH + lane * 2);
        }
#pragma unroll
        for (int j = 0; j < 8; ++j) if (j < (int)m) {
          float wpe = __uint_as_float(eb[j].y), pj = __uint_as_float(eb[j].z);
          dv0 += wpe * (bf2f(vr[j] & 0xFFFFu) - pj * Kr.x);
          dv1 += wpe * (bf2f(vr[j] >> 16) - pj * Kr.y);
          dk0 += wpe * (bf2f(hr[j] & 0xFFFFu) - Kr.x);
          dk1 += wpe * (bf2f(hr[j] >> 16) - Kr.y);
        }
      }
      *(float2*)(A.sv + roff) = make_float2(0.99f * V.x + 0.1f * dv0, 0.99f * V.y + 0.1f * dv1);
      if (n > 0u) {
        float u0 = Kr.x + 0.1f * dk0, u1 = Kr.y + 0.1f * dk1;
        float ssq = u0 * u0 + u1 * u1;
#pragma unroll
        for (int sh = 1; sh < 64; sh <<= 1) ssq += __shfl_xor(ssq, sh);
        float inv = 1.0f / (sqrtf(ssq) + 1e-6f);
        u0 *= inv; u1 *= inv;
        *(float2*)(A.sk + roff) = make_float2(u0, u1);
        *(u32*)(A.skb + roff) = pack2(u0, u1);
      }
      if (lane == 0)
        __hip_atomic_store(&A.cnt[slotoff], 0u, __ATOMIC_RELAXED, __HIP_MEMORY_SCOPE_AGENT);
    }
    bh_barrier(bcnt, bgen);
  }
}

// ---------------------------------------------------------------------------
// Kernel 4: output projection (unchanged from R1)
// ---------------------------------------------------------------------------
__global__ __launch_bounds__(256) void out_gemm(
    const float* __restrict__ yin, const float* __restrict__ w,
    const float* __restrict__ bias, float* __restrict__ out) {
  __shared__ u16 As[128 * 72];
  __shared__ u16 Bs[128 * 72];
  const int tid = threadIdx.x;
  const int lane = tid & 63, wv = tid >> 6;
  const int quad = lane >> 4, l15 = lane & 15;
  const int m0 = blockIdx.y * 128, n0 = blockIdx.x * 128;
  const int wr = wv >> 1, wc = wv & 1;
  f32x4 acc[4][4];
#pragma unroll
  for (int i = 0; i < 4; ++i)
#pragma unroll
    for (int j = 0; j < 4; ++j) acc[i][j] = f32x4{0.f, 0.f, 0.f, 0.f};
  const int f4c = tid & 15, r0 = tid >> 4;
  for (int kt = 0; kt < 16; ++kt) {
#pragma unroll
    for (int i = 0; i < 8; ++i) {
      int row = r0 + i * 16;
      float4 a = *(const float4*)(yin + (size_t)(m0 + row) * 1024 + kt * 64 + f4c * 4);
      float4 b = *(const float4*)(w + (size_t)(n0 + row) * 1024 + kt * 64 + f4c * 4);
      *(uint2*)(&As[row * 72 + f4c * 4]) = make_uint2(pack2(a.x, a.y), pack2(a.z, a.w));
      *(uint2*)(&Bs[row * 72 + f4c * 4]) = make_uint2(pack2(b.x, b.y), pack2(b.z, b.w));
    }
    __syncthreads();
#pragma unroll
    for (int ks = 0; ks < 2; ++ks) {
      bf16x8 af[4], bff[4];
#pragma unroll
      for (int rt = 0; rt < 4; ++rt)
        af[rt] = *(const bf16x8*)(&As[(wr * 64 + rt * 16 + l15) * 72 + ks * 32 + quad * 8]);
#pragma unroll
      for (int ct = 0; ct < 4; ++ct)
        bff[ct] = *(const bf16x8*)(&Bs[(wc * 64 + ct * 16 + l15) * 72 + ks * 32 + quad * 8]);
#pragma unroll
      for (int rt = 0; rt < 4; ++rt)
#pragma unroll
        for (int ct = 0; ct < 4; ++ct)
          acc[rt][ct] = __builtin_amdgcn_mfma_f32_16x16x32_bf16(af[rt], bff[ct], acc[rt][ct], 0, 0, 0);
    }
    __syncthreads();
  }
#pragma unroll
  for (int ct = 0; ct < 4; ++ct) {
    int n = n0 + wc * 64 + ct * 16 + l15;
    float bv = bias[n];
#pragma unroll
    for (int rt = 0; rt < 4; ++rt)
#pragma unroll
      for (int rg = 0; rg < 4; ++rg) {
        int m = m0 + wr * 64 + rt * 16 + quad * 4 + rg;
        out[(size_t)m * 1024 + n] = acc[rt][ct][rg] + bv;
      }
  }
}

// ---------------------------------------------------------------------------
extern "C" void kernel_launch(void* const* d_in, const int* in_sizes, int n_in,
                              void* d_out, int out_size, void* d_ws, size_t ws_size,
                              hipStream_t stream) {
  const float* x = (const float*)d_in[0];
  const float* Wqkv = (const float*)d_in[1];
  const float* bqkv = (const float*)d_in[2];
  const float* Wo = (const float*)d_in[3];
  const float* bo = (const float*)d_in[4];
  const float* Sinit = (const float*)d_in[5];
  const float* temp = (const float*)d_in[6];
  float* out = (float*)d_out;

  char* p = (char*)d_ws;
  auto take = [&](size_t bytes) { char* r = p; p += (bytes + 255) & ~(size_t)255; return r; };
  u16* qhb = (u16*)take((size_t)NBH * T2 * DH * 2);
  u16* khb = (u16*)take((size_t)NBH * T2 * DH * 2);
  u16* vhb = (u16*)take((size_t)NBH * T2 * DH * 2);
  float* yin = (float*)take((size_t)B2 * T2 * D2 * 4);
  float* sk = (float*)take((size_t)NBH * KSL * DH * 4);
  float* sv = (float*)take((size_t)NBH * KSL * DH * 4);
  u16* skb = (u16*)take((size_t)NBH * KSL * DH * 2);
  u16* khatb = (u16*)take((size_t)NBH * CH * DH * 2);
  u32* cnt = (u32*)take((size_t)NBH * KSL * 4);
  uint4* entries = (uint4*)take((size_t)NBH * KSL * 128 * 16);
  u32* barcnt = (u32*)take(64 * 4);
  u32* bargen = (u32*)take(64 * 4);
  u32* ready = (u32*)take(NBH * 16 * 4);

  hipLaunchKernelGGL(qkv_gemm, dim3(24, 32), dim3(256), 0, stream, x, Wqkv, bqkv, qhb, khb, vhb);
  hipLaunchKernelGGL(attn_kernel, dim3(16, 16), dim3(256), 0, stream, qhb, khb, vhb, yin);
  ScanArgs sa{qhb, khb, vhb, yin, sk, sv, skb, khatb, cnt, entries, barcnt, bargen, ready, Sinit, temp};
  hipLaunchKernelGGL(scan_kernel, dim3(256), dim3(512), 0, stream, sa);
  hipLaunchKernelGGL(out_gemm, dim3(8, 32), dim3(256), 0, stream, yin, Wo, bo, out);
}

// Round 3
// 1641.908 us; speedup vs baseline: 1.2760x; 1.2060x over previous
//
#include <hip/hip_runtime.h>

typedef unsigned short u16;
typedef unsigned int u32;
typedef unsigned long long u64;
typedef __attribute__((ext_vector_type(8))) short bf16x8;
typedef __attribute__((ext_vector_type(4))) float f32x4;

#define B2 2
#define T2 2048
#define D2 1024
#define H2 8
#define DH 128
#define KSL 512
#define CH 128
#define NCH 16
#define NBH 16
#define MAGIC 0x13579BDFu

__device__ __forceinline__ float bf2f(u32 h) { union { u32 u; float f; } x; x.u = h << 16; return x.f; }
__device__ __forceinline__ u16 f2bf(float f) {
  union { float f; u32 u; } x; x.f = f;
  return (u16)((x.u + 0x7FFFu + ((x.u >> 16) & 1u)) >> 16);
}
__device__ __forceinline__ u32 pack2(float a, float b) { return (u32)f2bf(a) | ((u32)f2bf(b) << 16); }

// ---------------------------------------------------------------------------
// Kernel 1: fused QKV projection (unchanged)
// ---------------------------------------------------------------------------
__global__ __launch_bounds__(256) void qkv_gemm(
    const float* __restrict__ x, const float* __restrict__ w,
    const float* __restrict__ bias, u16* __restrict__ qhb,
    u16* __restrict__ khb, u16* __restrict__ vhb) {
  __shared__ u16 As[128 * 72];
  __shared__ u16 Bs[128 * 72];
  const int tid = threadIdx.x;
  const int lane = tid & 63, wv = tid >> 6;
  const int quad = lane >> 4, l15 = lane & 15;
  const int m0 = blockIdx.y * 128, n0 = blockIdx.x * 128;
  const int wr = wv >> 1, wc = wv & 1;
  f32x4 acc[4][4];
#pragma unroll
  for (int i = 0; i < 4; ++i)
#pragma unroll
    for (int j = 0; j < 4; ++j) acc[i][j] = f32x4{0.f, 0.f, 0.f, 0.f};
  const int f4c = tid & 15, r0 = tid >> 4;
  for (int kt = 0; kt < 16; ++kt) {
#pragma unroll
    for (int i = 0; i < 8; ++i) {
      int row = r0 + i * 16;
      float4 a = *(const float4*)(x + (size_t)(m0 + row) * 1024 + kt * 64 + f4c * 4);
      float4 b = *(const float4*)(w + (size_t)(n0 + row) * 1024 + kt * 64 + f4c * 4);
      *(uint2*)(&As[row * 72 + f4c * 4]) = make_uint2(pack2(a.x, a.y), pack2(a.z, a.w));
      *(uint2*)(&Bs[row * 72 + f4c * 4]) = make_uint2(pack2(b.x, b.y), pack2(b.z, b.w));
    }
    __syncthreads();
#pragma unroll
    for (int ks = 0; ks < 2; ++ks) {
      bf16x8 af[4], bff[4];
#pragma unroll
      for (int rt = 0; rt < 4; ++rt)
        af[rt] = *(const bf16x8*)(&As[(wr * 64 + rt * 16 + l15) * 72 + ks * 32 + quad * 8]);
#pragma unroll
      for (int ct = 0; ct < 4; ++ct)
        bff[ct] = *(const bf16x8*)(&Bs[(wc * 64 + ct * 16 + l15) * 72 + ks * 32 + quad * 8]);
#pragma unroll
      for (int rt = 0; rt < 4; ++rt)
#pragma unroll
        for (int ct = 0; ct < 4; ++ct)
          acc[rt][ct] = __builtin_amdgcn_mfma_f32_16x16x32_bf16(af[rt], bff[ct], acc[rt][ct], 0, 0, 0);
    }
    __syncthreads();
  }
#pragma unroll
  for (int ct = 0; ct < 4; ++ct) {
    int n = n0 + wc * 64 + ct * 16 + l15;
    float bv = bias[n];
    int sec = n >> 10, rr2 = n & 1023, hh = rr2 >> 7, dd = rr2 & 127;
    u16* dst = (sec == 0) ? qhb : (sec == 1) ? khb : vhb;
#pragma unroll
    for (int rt = 0; rt < 4; ++rt)
#pragma unroll
      for (int rg = 0; rg < 4; ++rg) {
        int m = m0 + wr * 64 + rt * 16 + quad * 4 + rg;
        int bb = m >> 11, tt = m & 2047;
        dst[((size_t)(bb * 8 + hh) * T2 + tt) * DH + dd] = f2bf(acc[rt][ct][rg] + bv);
      }
  }
}

// ---------------------------------------------------------------------------
// Kernel 2: sliding-window attention (unchanged)
// ---------------------------------------------------------------------------
__global__ __launch_bounds__(256) void attn_kernel(
    const u16* __restrict__ qhb, const u16* __restrict__ khb,
    const u16* __restrict__ vhb, float* __restrict__ yin) {
  __shared__ u16 Pls[128 * 72];
  __shared__ u16 VT[128 * 72];
  const int tid = threadIdx.x;
  const int lane = tid & 63, wv = tid >> 6;
  const int quad = lane >> 4, l15 = lane & 15;
  const int bh = blockIdx.y, qt = blockIdx.x;
  const int t0 = qt * 128;
  const int b = bh >> 3, h = bh & 7;
  f32x4 Oa[2][8];
  float mrow[2][4], lrow[2][4];
#pragma unroll
  for (int rt = 0; rt < 2; ++rt) {
#pragma unroll
    for (int dt = 0; dt < 8; ++dt) Oa[rt][dt] = f32x4{0.f, 0.f, 0.f, 0.f};
#pragma unroll
    for (int rg = 0; rg < 4; ++rg) { mrow[rt][rg] = -1e30f; lrow[rt][rg] = 0.f; }
  }
  const u16* qbase = qhb + ((size_t)bh * T2 + t0) * DH;
  int j0 = t0 / 64 - 8; if (j0 < 0) j0 = 0;
  int j1 = t0 / 64 + 1;
  for (int jt = j0; jt <= j1; ++jt) {
    int kv0 = jt * 64;
    __syncthreads();
    {
      int r = tid & 63, dq = tid >> 6;
      const u16* vrow = vhb + ((size_t)bh * T2 + kv0 + r) * DH + dq * 32;
#pragma unroll
      for (int u = 0; u < 4; ++u) {
        uint4 pv = *(const uint4*)(vrow + u * 8);
        int d0 = dq * 32 + u * 8;
        VT[(d0 + 0) * 72 + r] = (u16)(pv.x); VT[(d0 + 1) * 72 + r] = (u16)(pv.x >> 16);
        VT[(d0 + 2) * 72 + r] = (u16)(pv.y); VT[(d0 + 3) * 72 + r] = (u16)(pv.y >> 16);
        VT[(d0 + 4) * 72 + r] = (u16)(pv.z); VT[(d0 + 5) * 72 + r] = (u16)(pv.z >> 16);
        VT[(d0 + 6) * 72 + r] = (u16)(pv.w); VT[(d0 + 7) * 72 + r] = (u16)(pv.w >> 16);
      }
    }
    f32x4 Sa[2][4];
#pragma unroll
    for (int rt = 0; rt < 2; ++rt)
#pragma unroll
      for (int ct = 0; ct < 4; ++ct) Sa[rt][ct] = f32x4{0.f, 0.f, 0.f, 0.f};
#pragma unroll
    for (int ks = 0; ks < 4; ++ks) {
      bf16x8 a0 = *(const bf16x8*)(qbase + (size_t)(wv * 32 + l15) * DH + ks * 32 + quad * 8);
      bf16x8 a1 = *(const bf16x8*)(qbase + (size_t)(wv * 32 + 16 + l15) * DH + ks * 32 + quad * 8);
#pragma unroll
      for (int ct = 0; ct < 4; ++ct) {
        bf16x8 bb = *(const bf16x8*)(khb + ((size_t)bh * T2 + kv0 + ct * 16 + l15) * DH + ks * 32 + quad * 8);
        Sa[0][ct] = __builtin_amdgcn_mfma_f32_16x16x32_bf16(a0, bb, Sa[0][ct], 0, 0, 0);
        Sa[1][ct] = __builtin_amdgcn_mfma_f32_16x16x32_bf16(a1, bb, Sa[1][ct], 0, 0, 0);
      }
    }
#pragma unroll
    for (int rt = 0; rt < 2; ++rt)
#pragma unroll
      for (int rg = 0; rg < 4; ++rg) {
        int row = wv * 32 + rt * 16 + quad * 4 + rg;
        int qp = t0 + row;
        float vals[4];
        float mx = -1e30f;
#pragma unroll
        for (int ct = 0; ct < 4; ++ct) {
          int kp = kv0 + ct * 16 + l15;
          float s = Sa[rt][ct][rg] * 0.08838834764831845f;
          bool ok = (kp <= qp) && (kp + 512 > qp);
          s = ok ? s : -1e30f;
          vals[ct] = s;
          mx = fmaxf(mx, s);
        }
#pragma unroll
        for (int sh = 1; sh < 16; sh <<= 1) mx = fmaxf(mx, __shfl_xor(mx, sh));
        float mold = mrow[rt][rg];
        float mnew = fmaxf(mold, mx);
        float alpha = __expf(mold - mnew);
        float rsum = 0.f;
        float pv_[4];
#pragma unroll
        for (int ct = 0; ct < 4; ++ct) {
          float p = (vals[ct] < -1e29f) ? 0.f : __expf(vals[ct] - mnew);
          pv_[ct] = p; rsum += p;
        }
#pragma unroll
        for (int sh = 1; sh < 16; sh <<= 1) rsum += __shfl_xor(rsum, sh);
        lrow[rt][rg] = lrow[rt][rg] * alpha + rsum;
        mrow[rt][rg] = mnew;
#pragma unroll
        for (int dt = 0; dt < 8; ++dt) Oa[rt][dt][rg] *= alpha;
#pragma unroll
        for (int ct = 0; ct < 4; ++ct) Pls[row * 72 + ct * 16 + l15] = f2bf(pv_[ct]);
      }
    __syncthreads();
#pragma unroll
    for (int ks = 0; ks < 2; ++ks) {
      bf16x8 a0 = *(const bf16x8*)(&Pls[(wv * 32 + l15) * 72 + ks * 32 + quad * 8]);
      bf16x8 a1 = *(const bf16x8*)(&Pls[(wv * 32 + 16 + l15) * 72 + ks * 32 + quad * 8]);
#pragma unroll
      for (int dt = 0; dt < 8; ++dt) {
        bf16x8 bb = *(const bf16x8*)(&VT[(dt * 16 + l15) * 72 + ks * 32 + quad * 8]);
        Oa[0][dt] = __builtin_amdgcn_mfma_f32_16x16x32_bf16(a0, bb, Oa[0][dt], 0, 0, 0);
        Oa[1][dt] = __builtin_amdgcn_mfma_f32_16x16x32_bf16(a1, bb, Oa[1][dt], 0, 0, 0);
      }
    }
  }
#pragma unroll
  for (int rt = 0; rt < 2; ++rt)
#pragma unroll
    for (int rg = 0; rg < 4; ++rg) {
      int row = wv * 32 + rt * 16 + quad * 4 + rg;
      float invl = 1.0f / lrow[rt][rg];
#pragma unroll
      for (int dt = 0; dt < 8; ++dt)
        yin[((size_t)b * T2 + t0 + row) * D2 + h * DH + dt * 16 + l15] = Oa[rt][dt][rg] * invl;
    }
}

// ---------------------------------------------------------------------------
// Kernel 3: slot-memory scan v3.
// XCD-affinity: xcd = blockIdx%8 (dispatch round-robin heuristic); 2 bh per
// XCD so each bh's 16 blocks + its whole slot state stay in one L2.
// Fused A1+A3: one MFMA pass, C-rows 0-7 = q-scores, 8-15 = khat-scores.
// Per chunk: 2 __syncthreads + 2 device barriers.
// ---------------------------------------------------------------------------
struct ScanArgs {
  const u16* qhb; const u16* khb; const u16* vhb;
  float* yin; float* sk; float* sv; u16* skb; u16* khatb;
  u32* cnt; uint4* entries;
  u32* barcnt; u32* bargen; u32* ready;
  const float* sinit; const float* temp;
};

__device__ void bh_barrier(u32* cnt, u32* gen) {
  __syncthreads();
  if (threadIdx.x == 0) {
    __threadfence();
    u32 g = __hip_atomic_load(gen, __ATOMIC_RELAXED, __HIP_MEMORY_SCOPE_AGENT);
    u32 a = __hip_atomic_fetch_add(cnt, 1u, __ATOMIC_ACQ_REL, __HIP_MEMORY_SCOPE_AGENT);
    if (a == 15u) {
      __hip_atomic_store(cnt, 0u, __ATOMIC_RELAXED, __HIP_MEMORY_SCOPE_AGENT);
      __hip_atomic_store(gen, g + 1u, __ATOMIC_RELEASE, __HIP_MEMORY_SCOPE_AGENT);
    } else {
      while (__hip_atomic_load(gen, __ATOMIC_ACQUIRE, __HIP_MEMORY_SCOPE_AGENT) == g)
        __builtin_amdgcn_s_sleep(2);
    }
    __threadfence();
  }
  __syncthreads();
}

__device__ __forceinline__ void topk16(const float* rowp, int lane, volatile u64* candw,
                                       float& p_out, u32& idx_out) {
  u32 mono[8];
#pragma unroll
  for (int j = 0; j < 8; ++j) {
    float f = rowp[j * 64 + lane];
    u32 u = __float_as_uint(f);
    mono[j] = ((int)u < 0) ? ~u : (u | 0x80000000u);
  }
  u32 mx = mono[0];
#pragma unroll
  for (int j = 1; j < 8; ++j) mx = max(mx, mono[j]);
  u32 s = mx;
#pragma unroll
  for (int k = 2; k <= 64; k <<= 1) {
#pragma unroll
    for (int j = k >> 1; j > 0; j >>= 1) {
      u32 o = (u32)__shfl_xor((int)s, j);
      bool keep_min = (((lane & k) == 0) == ((lane & j) == 0));
      u32 mn = min(s, o), mxx = max(s, o);
      s = keep_min ? mn : mxx;
    }
  }
  u32 thr = (u32)__shfl((int)s, 48);
  u32 base = 0;
#pragma unroll
  for (int j = 0; j < 8; ++j) {
    bool pred = (mono[j] >= thr);
    u64 mask = __ballot(pred);
    u32 pos = base + (u32)__popcll(mask & ((1ull << lane) - 1ull));
    if (pred && pos < 64u)
      candw[pos] = (((u64)mono[j]) << 32) | (u64)(0xFFFFFFFFu - (u32)(j * 64 + lane));
    base += (u32)__popcll(mask);
  }
  __threadfence_block();
  u32 cntc = base < 64u ? base : 64u;
  u64 key = ((u32)lane < cntc) ? candw[lane] : 0ull;
#pragma unroll
  for (int k = 2; k <= 64; k <<= 1) {
#pragma unroll
    for (int j = k >> 1; j > 0; j >>= 1) {
      u64 o = __shfl_xor(key, j);
      bool keep_min = (((lane & k) == 0) == ((lane & j) == 0));
      u64 mn = key < o ? key : o;
      u64 mxx = key < o ? o : key;
      key = keep_min ? mn : mxx;
    }
  }
  u32 um = (u32)(key >> 32);
  float val = __uint_as_float((um & 0x80000000u) ? (um & 0x7FFFFFFFu) : ~um);
  idx_out = 0xFFFFFFFFu - (u32)(key & 0xFFFFFFFFull);
  float mtop = __shfl(val, 63);
  float e = __expf(val - mtop);
  float ssum = e;
#pragma unroll
  for (int sh = 1; sh < 16; sh <<= 1) ssum += __shfl_xor(ssum, sh);
  p_out = e / ssum;
}

__global__ __launch_bounds__(512, 2) void scan_kernel(ScanArgs A) {
  const int tid = threadIdx.x;
  const int lane = tid & 63, wv = tid >> 6;
  const int quad = lane >> 4, l15 = lane & 15;
  // XCD-affinity mapping: blocks i with i%8==x go to XCD x (heuristic).
  const int xcd = blockIdx.x & 7;
  const int wi = blockIdx.x >> 3;           // 0..31 within XCD
  const int bh = xcd * 2 + (wi >> 4);       // 2 bh per XCD
  const int blk = wi & 15;                  // 16 blocks per bh
  const int b = bh >> 3, h = bh & 7;
  __shared__ u16 khat_ls[8 * 136];
  __shared__ float scores_r[8 * 520];
  __shared__ float scores_w[8 * 520];
  __shared__ u64 cand[8][64];

  const float invtemp = 1.0f / A.temp[0];
  const float sc_r = 0.08838834764831845f * invtemp;

  // ---- init: this block's 32 slots (4 per wave) ----
#pragma unroll 1
  for (int i = 0; i < 4; ++i) {
    int s = blk * 32 + wv * 4 + i;
    float2 v2 = *(const float2*)(A.sinit + (size_t)s * 1024 + h * 128 + lane * 2);
    float ssq = v2.x * v2.x + v2.y * v2.y;
#pragma unroll
    for (int sh = 1; sh < 64; sh <<= 1) ssq += __shfl_xor(ssq, sh);
    float inv = 1.0f / (sqrtf(ssq) + 1e-6f);
    size_t off = ((size_t)bh * KSL + s) * DH + lane * 2;
    *(float2*)(A.sk + off) = make_float2(v2.x * inv, v2.y * inv);
    *(float2*)(A.sv + off) = v2;
    *(u32*)(A.skb + off) = pack2(v2.x * inv, v2.y * inv);
    if (lane == 0)
      __hip_atomic_store(&A.cnt[bh * KSL + s], 0u, __ATOMIC_RELAXED, __HIP_MEMORY_SCOPE_AGENT);
  }
  if (blk == 0 && tid == 0) { A.barcnt[bh] = 0u; A.bargen[bh] = 0u; }
  __syncthreads();
  if (tid == 0) {  // ready-flag gate (works on 0xAA-poisoned memory)
    __threadfence();
    __hip_atomic_store(&A.ready[bh * 16 + blk], MAGIC, __ATOMIC_RELEASE, __HIP_MEMORY_SCOPE_AGENT);
    for (int i = 0; i < 16; ++i)
      while (__hip_atomic_load(&A.ready[bh * 16 + i], __ATOMIC_ACQUIRE, __HIP_MEMORY_SCOPE_AGENT) != MAGIC)
        __builtin_amdgcn_s_sleep(2);
    __threadfence();
  }
  __syncthreads();

  u32* bcnt = A.barcnt + bh;
  u32* bgen = A.bargen + bh;

#pragma unroll 1
  for (int ci = 0; ci < NCH; ++ci) {
    const int t0base = ci * CH;
    const int c = blk * 8 + wv;          // this wave's chunk-row
    const int trow = t0base + c;
    // ---- A0: k-hat for row c ----
    {
      u32 kraw = *(const u32*)(A.khb + ((size_t)bh * T2 + trow) * DH + lane * 2);
      float k0 = bf2f(kraw & 0xFFFFu), k1 = bf2f(kraw >> 16);
      float ssq = k0 * k0 + k1 * k1;
#pragma unroll
      for (int sh = 1; sh < 64; sh <<= 1) ssq += __shfl_xor(ssq, sh);
      float inv = 1.0f / (sqrtf(ssq) + 1e-6f);
      u32 pk = pack2(k0 * inv, k1 * inv);
      *(u32*)(&khat_ls[wv * 136 + lane * 2]) = pk;
      *(u32*)(A.khatb + ((size_t)bh * CH + c) * DH + lane * 2) = pk;
    }
    __syncthreads();
    // ---- A13: fused scores. A-rows 0-7 = q rows, 8-15 = khat rows. ----
    {
      const u16* qbase = A.qhb + ((size_t)bh * T2 + t0base + blk * 8) * DH;
      const u16* sbase = A.skb + (size_t)bh * KSL * DH;
      f32x4 acc[4];
#pragma unroll
      for (int ct = 0; ct < 4; ++ct) acc[ct] = f32x4{0.f, 0.f, 0.f, 0.f};
#pragma unroll
      for (int ks = 0; ks < 4; ++ks) {
        bf16x8 a;
        if (l15 < 8)
          a = *(const bf16x8*)(qbase + (size_t)l15 * DH + ks * 32 + quad * 8);
        else
          a = *(const bf16x8*)(&khat_ls[(l15 - 8) * 136 + ks * 32 + quad * 8]);
#pragma unroll
        for (int ct = 0; ct < 4; ++ct) {
          bf16x8 bb = *(const bf16x8*)(sbase + (size_t)(wv * 64 + ct * 16 + l15) * DH + ks * 32 + quad * 8);
          acc[ct] = __builtin_amdgcn_mfma_f32_16x16x32_bf16(a, bb, acc[ct], 0, 0, 0);
        }
      }
#pragma unroll
      for (int ct = 0; ct < 4; ++ct)
#pragma unroll
        for (int rg = 0; rg < 4; ++rg) {
          int m = quad * 4 + rg;
          int col = wv * 64 + ct * 16 + l15;
          if (m < 8) scores_r[m * 520 + col] = acc[ct][rg] * sc_r;
          else       scores_w[(m - 8) * 520 + col] = acc[ct][rg];
        }
    }
    __syncthreads();
    // ---- A24: both top-16s; read-gather into yin; write-append entries ----
    {
      float p; u32 sidx;
      topk16(&scores_r[wv * 520], lane, cand[wv], p, sidx);
      float acc0 = 0.f, acc1 = 0.f;
      const float* svb = A.sv + (size_t)bh * KSL * DH;
#pragma unroll
      for (int r = 0; r < 16; ++r) {
        float pr = __shfl(p, 63 - r);
        u32 ir = (u32)__shfl((int)sidx, 63 - r);
        float2 vv = *(const float2*)(svb + (size_t)ir * DH + lane * 2);
        acc0 += pr * vv.x; acc1 += pr * vv.y;
      }
      float* yp = A.yin + ((size_t)b * T2 + trow) * D2 + h * DH + lane * 2;
      yp[0] += acc0; yp[1] += acc1;

      float wp; u32 widx;
      topk16(&scores_w[wv * 520], lane, cand[wv], wp, widx);
      const int r = lane >> 2, g = lane & 3;   // 16 picks x 4 lanes
      float wr = __shfl(wp, 63 - r);
      u32 ir = (u32)__shfl((int)widx, 63 - r);
      const float* kb = A.sk + ((size_t)bh * KSL + ir) * DH + g * 32;
      const u16* vb = A.vhb + ((size_t)bh * T2 + trow) * DH + g * 32;
      float part = 0.f;
#pragma unroll
      for (int u2 = 0; u2 < 4; ++u2) {
        uint4 vvp = *(const uint4*)(vb + u2 * 8);
        float4 k0 = *(const float4*)(kb + u2 * 8);
        float4 k1 = *(const float4*)(kb + u2 * 8 + 4);
        part += bf2f(vvp.x & 0xFFFFu) * k0.x + bf2f(vvp.x >> 16) * k0.y
              + bf2f(vvp.y & 0xFFFFu) * k0.z + bf2f(vvp.y >> 16) * k0.w
              + bf2f(vvp.z & 0xFFFFu) * k1.x + bf2f(vvp.z >> 16) * k1.y
              + bf2f(vvp.w & 0xFFFFu) * k1.z + bf2f(vvp.w >> 16) * k1.w;
      }
      part += __shfl_xor(part, 1);
      part += __shfl_xor(part, 2);
      if (g == 0) {
        u32 pos = atomicAdd(&A.cnt[bh * KSL + ir], 1u);
        A.entries[((size_t)bh * KSL + ir) * 128 + pos] =
            make_uint4((u32)c, __float_as_uint(wr), __float_as_uint(part), 0u);
      }
    }
    bh_barrier(bcnt, bgen);
    // ---- B: each owned slot pulls its updates (batch-8 entry loads) ----
#pragma unroll 1
    for (int i = 0; i < 4; ++i) {
      int s = blk * 32 + wv * 4 + i;
      size_t slotoff = (size_t)bh * KSL + s;
      size_t roff = slotoff * DH + lane * 2;
      u32 n = __hip_atomic_load(&A.cnt[slotoff], __ATOMIC_RELAXED, __HIP_MEMORY_SCOPE_AGENT);
      float2 V = *(const float2*)(A.sv + roff);
      float2 Kr = *(const float2*)(A.sk + roff);
      float dv0 = 0, dv1 = 0, dk0 = 0, dk1 = 0;
      u32 nd = n < 128u ? n : 128u;
      const uint4* ebase = A.entries + slotoff * 128;
#pragma unroll 1
      for (u32 base2 = 0; base2 < nd; base2 += 8) {
        u32 m = nd - base2; if (m > 8u) m = 8u;
        uint4 eb[8];
#pragma unroll
        for (int j = 0; j < 8; ++j) if (j < (int)m) eb[j] = ebase[base2 + j];
        u32 vr[8], hr[8];
#pragma unroll
        for (int j = 0; j < 8; ++j) if (j < (int)m) {
          u32 c2 = eb[j].x;
          vr[j] = *(const u32*)(A.vhb + ((size_t)bh * T2 + t0base + c2) * DH + lane * 2);
          hr[j] = *(const u32*)(A.khatb + ((size_t)bh * CH + c2) * DH + lane * 2);
        }
#pragma unroll
        for (int j = 0; j < 8; ++j) if (j < (int)m) {
          float wpe = __uint_as_float(eb[j].y), pj = __uint_as_float(eb[j].z);
          dv0 += wpe * (bf2f(vr[j] & 0xFFFFu) - pj * Kr.x);
          dv1 += wpe * (bf2f(vr[j] >> 16) - pj * Kr.y);
          dk0 += wpe * (bf2f(hr[j] & 0xFFFFu) - Kr.x);
          dk1 += wpe * (bf2f(hr[j] >> 16) - Kr.y);
        }
      }
      *(float2*)(A.sv + roff) = make_float2(0.99f * V.x + 0.1f * dv0, 0.99f * V.y + 0.1f * dv1);
      if (n > 0u) {
        float u0 = Kr.x + 0.1f * dk0, u1 = Kr.y + 0.1f * dk1;
        float ssq = u0 * u0 + u1 * u1;
#pragma unroll
        for (int sh = 1; sh < 64; sh <<= 1) ssq += __shfl_xor(ssq, sh);
        float inv = 1.0f / (sqrtf(ssq) + 1e-6f);
        u0 *= inv; u1 *= inv;
        *(float2*)(A.sk + roff) = make_float2(u0, u1);
        *(u32*)(A.skb + roff) = pack2(u0, u1);
      }
      if (lane == 0)
        __hip_atomic_store(&A.cnt[slotoff], 0u, __ATOMIC_RELAXED, __HIP_MEMORY_SCOPE_AGENT);
    }
    bh_barrier(bcnt, bgen);
  }
}

// ---------------------------------------------------------------------------
// Kernel 4: output projection (unchanged)
// ---------------------------------------------------------------------------
__global__ __launch_bounds__(256) void out_gemm(
    const float* __restrict__ yin, const float* __restrict__ w,
    const float* __restrict__ bias, float* __restrict__ out) {
  __shared__ u16 As[128 * 72];
  __shared__ u16 Bs[128 * 72];
  const int tid = threadIdx.x;
  const int lane = tid & 63, wv = tid >> 6;
  const int quad = lane >> 4, l15 = lane & 15;
  const int m0 = blockIdx.y * 128, n0 = blockIdx.x * 128;
  const int wr = wv >> 1, wc = wv & 1;
  f32x4 acc[4][4];
#pragma unroll
  for (int i = 0; i < 4; ++i)
#pragma unroll
    for (int j = 0; j < 4; ++j) acc[i][j] = f32x4{0.f, 0.f, 0.f, 0.f};
  const int f4c = tid & 15, r0 = tid >> 4;
  for (int kt = 0; kt < 16; ++kt) {
#pragma unroll
    for (int i = 0; i < 8; ++i) {
      int row = r0 + i * 16;
      float4 a = *(const float4*)(yin + (size_t)(m0 + row) * 1024 + kt * 64 + f4c * 4);
      float4 b = *(const float4*)(w + (size_t)(n0 + row) * 1024 + kt * 64 + f4c * 4);
      *(uint2*)(&As[row * 72 + f4c * 4]) = make_uint2(pack2(a.x, a.y), pack2(a.z, a.w));
      *(uint2*)(&Bs[row * 72 + f4c * 4]) = make_uint2(pack2(b.x, b.y), pack2(b.z, b.w));
    }
    __syncthreads();
#pragma unroll
    for (int ks = 0; ks < 2; ++ks) {
      bf16x8 af[4], bff[4];
#pragma unroll
      for (int rt = 0; rt < 4; ++rt)
        af[rt] = *(const bf16x8*)(&As[(wr * 64 + rt * 16 + l15) * 72 + ks * 32 + quad * 8]);
#pragma unroll
      for (int ct = 0; ct < 4; ++ct)
        bff[ct] = *(const bf16x8*)(&Bs[(wc * 64 + ct * 16 + l15) * 72 + ks * 32 + quad * 8]);
#pragma unroll
      for (int rt = 0; rt < 4; ++rt)
#pragma unroll
        for (int ct = 0; ct < 4; ++ct)
          acc[rt][ct] = __builtin_amdgcn_mfma_f32_16x16x32_bf16(af[rt], bff[ct], acc[rt][ct], 0, 0, 0);
    }
    __syncthreads();
  }
#pragma unroll
  for (int ct = 0; ct < 4; ++ct) {
    int n = n0 + wc * 64 + ct * 16 + l15;
    float bv = bias[n];
#pragma unroll
    for (int rt = 0; rt < 4; ++rt)
#pragma unroll
      for (int rg = 0; rg < 4; ++rg) {
        int m = m0 + wr * 64 + rt * 16 + quad * 4 + rg;
        out[(size_t)m * 1024 + n] = acc[rt][ct][rg] + bv;
      }
  }
}

// ---------------------------------------------------------------------------
extern "C" void kernel_launch(void* const* d_in, const int* in_sizes, int n_in,
                              void* d_out, int out_size, void* d_ws, size_t ws_size,
                              hipStream_t stream) {
  const float* x = (const float*)d_in[0];
  const float* Wqkv = (const float*)d_in[1];
  const float* bqkv = (const float*)d_in[2];
  const float* Wo = (const float*)d_in[3];
  const float* bo = (const float*)d_in[4];
  const float* Sinit = (const float*)d_in[5];
  const float* temp = (const float*)d_in[6];
  float* out = (float*)d_out;

  char* p = (char*)d_ws;
  auto take = [&](size_t bytes) { char* r = p; p += (bytes + 255) & ~(size_t)255; return r; };
  u16* qhb = (u16*)take((size_t)NBH * T2 * DH * 2);
  u16* khb = (u16*)take((size_t)NBH * T2 * DH * 2);
  u16* vhb = (u16*)take((size_t)NBH * T2 * DH * 2);
  float* yin = (float*)take((size_t)B2 * T2 * D2 * 4);
  float* sk = (float*)take((size_t)NBH * KSL * DH * 4);
  float* sv = (float*)take((size_t)NBH * KSL * DH * 4);
  u16* skb = (u16*)take((size_t)NBH * KSL * DH * 2);
  u16* khatb = (u16*)take((size_t)NBH * CH * DH * 2);
  u32* cnt = (u32*)take((size_t)NBH * KSL * 4);
  uint4* entries = (uint4*)take((size_t)NBH * KSL * 128 * 16);
  u32* barcnt = (u32*)take(64 * 4);
  u32* bargen = (u32*)take(64 * 4);
  u32* ready = (u32*)take(NBH * 16 * 4);

  hipLaunchKernelGGL(qkv_gemm, dim3(24, 32), dim3(256), 0, stream, x, Wqkv, bqkv, qhb, khb, vhb);
  hipLaunchKernelGGL(attn_kernel, dim3(16, 16), dim3(256), 0, stream, qhb, khb, vhb, yin);
  ScanArgs sa{qhb, khb, vhb, yin, sk, sv, skb, khatb, cnt, entries, barcnt, bargen, ready, Sinit, temp};
  hipLaunchKernelGGL(scan_kernel, dim3(256), dim3(512), 0, stream, sa);
  hipLaunchKernelGGL(out_gemm, dim3(8, 32), dim3(256), 0, stream, yin, Wo, bo, out);
}

// Round 4
// 1029.242 us; speedup vs baseline: 2.0355x; 1.5953x over previous
//
#include <hip/hip_runtime.h>

typedef unsigned short u16;
typedef unsigned int u32;
typedef unsigned long long u64;
typedef __attribute__((ext_vector_type(8))) short bf16x8;
typedef __attribute__((ext_vector_type(4))) float f32x4;

#define B2 2
#define T2 2048
#define D2 1024
#define H2 8
#define DH 128
#define KSL 512
#define CH 128
#define NCH 16
#define NBH 16
#define MAGIC 0x13579BDFu

__device__ __forceinline__ float bf2f(u32 h) { union { u32 u; float f; } x; x.u = h << 16; return x.f; }
__device__ __forceinline__ u16 f2bf(float f) {
  union { float f; u32 u; } x; x.f = f;
  return (u16)((x.u + 0x7FFFu + ((x.u >> 16) & 1u)) >> 16);
}
__device__ __forceinline__ u32 pack2(float a, float b) { return (u32)f2bf(a) | ((u32)f2bf(b) << 16); }

// ---------------------------------------------------------------------------
// Kernel 1: fused QKV projection (unchanged)
// ---------------------------------------------------------------------------
__global__ __launch_bounds__(256) void qkv_gemm(
    const float* __restrict__ x, const float* __restrict__ w,
    const float* __restrict__ bias, u16* __restrict__ qhb,
    u16* __restrict__ khb, u16* __restrict__ vhb) {
  __shared__ u16 As[128 * 72];
  __shared__ u16 Bs[128 * 72];
  const int tid = threadIdx.x;
  const int lane = tid & 63, wv = tid >> 6;
  const int quad = lane >> 4, l15 = lane & 15;
  const int m0 = blockIdx.y * 128, n0 = blockIdx.x * 128;
  const int wr = wv >> 1, wc = wv & 1;
  f32x4 acc[4][4];
#pragma unroll
  for (int i = 0; i < 4; ++i)
#pragma unroll
    for (int j = 0; j < 4; ++j) acc[i][j] = f32x4{0.f, 0.f, 0.f, 0.f};
  const int f4c = tid & 15, r0 = tid >> 4;
  for (int kt = 0; kt < 16; ++kt) {
#pragma unroll
    for (int i = 0; i < 8; ++i) {
      int row = r0 + i * 16;
      float4 a = *(const float4*)(x + (size_t)(m0 + row) * 1024 + kt * 64 + f4c * 4);
      float4 b = *(const float4*)(w + (size_t)(n0 + row) * 1024 + kt * 64 + f4c * 4);
      *(uint2*)(&As[row * 72 + f4c * 4]) = make_uint2(pack2(a.x, a.y), pack2(a.z, a.w));
      *(uint2*)(&Bs[row * 72 + f4c * 4]) = make_uint2(pack2(b.x, b.y), pack2(b.z, b.w));
    }
    __syncthreads();
#pragma unroll
    for (int ks = 0; ks < 2; ++ks) {
      bf16x8 af[4], bff[4];
#pragma unroll
      for (int rt = 0; rt < 4; ++rt)
        af[rt] = *(const bf16x8*)(&As[(wr * 64 + rt * 16 + l15) * 72 + ks * 32 + quad * 8]);
#pragma unroll
      for (int ct = 0; ct < 4; ++ct)
        bff[ct] = *(const bf16x8*)(&Bs[(wc * 64 + ct * 16 + l15) * 72 + ks * 32 + quad * 8]);
#pragma unroll
      for (int rt = 0; rt < 4; ++rt)
#pragma unroll
        for (int ct = 0; ct < 4; ++ct)
          acc[rt][ct] = __builtin_amdgcn_mfma_f32_16x16x32_bf16(af[rt], bff[ct], acc[rt][ct], 0, 0, 0);
    }
    __syncthreads();
  }
#pragma unroll
  for (int ct = 0; ct < 4; ++ct) {
    int n = n0 + wc * 64 + ct * 16 + l15;
    float bv = bias[n];
    int sec = n >> 10, rr2 = n & 1023, hh = rr2 >> 7, dd = rr2 & 127;
    u16* dst = (sec == 0) ? qhb : (sec == 1) ? khb : vhb;
#pragma unroll
    for (int rt = 0; rt < 4; ++rt)
#pragma unroll
      for (int rg = 0; rg < 4; ++rg) {
        int m = m0 + wr * 64 + rt * 16 + quad * 4 + rg;
        int bb = m >> 11, tt = m & 2047;
        dst[((size_t)(bb * 8 + hh) * T2 + tt) * DH + dd] = f2bf(acc[rt][ct][rg] + bv);
      }
  }
}

// ---------------------------------------------------------------------------
// Kernel 2: sliding-window attention (unchanged)
// ---------------------------------------------------------------------------
__global__ __launch_bounds__(256) void attn_kernel(
    const u16* __restrict__ qhb, const u16* __restrict__ khb,
    const u16* __restrict__ vhb, float* __restrict__ yin) {
  __shared__ u16 Pls[128 * 72];
  __shared__ u16 VT[128 * 72];
  const int tid = threadIdx.x;
  const int lane = tid & 63, wv = tid >> 6;
  const int quad = lane >> 4, l15 = lane & 15;
  const int bh = blockIdx.y, qt = blockIdx.x;
  const int t0 = qt * 128;
  const int b = bh >> 3, h = bh & 7;
  f32x4 Oa[2][8];
  float mrow[2][4], lrow[2][4];
#pragma unroll
  for (int rt = 0; rt < 2; ++rt) {
#pragma unroll
    for (int dt = 0; dt < 8; ++dt) Oa[rt][dt] = f32x4{0.f, 0.f, 0.f, 0.f};
#pragma unroll
    for (int rg = 0; rg < 4; ++rg) { mrow[rt][rg] = -1e30f; lrow[rt][rg] = 0.f; }
  }
  const u16* qbase = qhb + ((size_t)bh * T2 + t0) * DH;
  int j0 = t0 / 64 - 8; if (j0 < 0) j0 = 0;
  int j1 = t0 / 64 + 1;
  for (int jt = j0; jt <= j1; ++jt) {
    int kv0 = jt * 64;
    __syncthreads();
    {
      int r = tid & 63, dq = tid >> 6;
      const u16* vrow = vhb + ((size_t)bh * T2 + kv0 + r) * DH + dq * 32;
#pragma unroll
      for (int u = 0; u < 4; ++u) {
        uint4 pv = *(const uint4*)(vrow + u * 8);
        int d0 = dq * 32 + u * 8;
        VT[(d0 + 0) * 72 + r] = (u16)(pv.x); VT[(d0 + 1) * 72 + r] = (u16)(pv.x >> 16);
        VT[(d0 + 2) * 72 + r] = (u16)(pv.y); VT[(d0 + 3) * 72 + r] = (u16)(pv.y >> 16);
        VT[(d0 + 4) * 72 + r] = (u16)(pv.z); VT[(d0 + 5) * 72 + r] = (u16)(pv.z >> 16);
        VT[(d0 + 6) * 72 + r] = (u16)(pv.w); VT[(d0 + 7) * 72 + r] = (u16)(pv.w >> 16);
      }
    }
    f32x4 Sa[2][4];
#pragma unroll
    for (int rt = 0; rt < 2; ++rt)
#pragma unroll
      for (int ct = 0; ct < 4; ++ct) Sa[rt][ct] = f32x4{0.f, 0.f, 0.f, 0.f};
#pragma unroll
    for (int ks = 0; ks < 4; ++ks) {
      bf16x8 a0 = *(const bf16x8*)(qbase + (size_t)(wv * 32 + l15) * DH + ks * 32 + quad * 8);
      bf16x8 a1 = *(const bf16x8*)(qbase + (size_t)(wv * 32 + 16 + l15) * DH + ks * 32 + quad * 8);
#pragma unroll
      for (int ct = 0; ct < 4; ++ct) {
        bf16x8 bb = *(const bf16x8*)(khb + ((size_t)bh * T2 + kv0 + ct * 16 + l15) * DH + ks * 32 + quad * 8);
        Sa[0][ct] = __builtin_amdgcn_mfma_f32_16x16x32_bf16(a0, bb, Sa[0][ct], 0, 0, 0);
        Sa[1][ct] = __builtin_amdgcn_mfma_f32_16x16x32_bf16(a1, bb, Sa[1][ct], 0, 0, 0);
      }
    }
#pragma unroll
    for (int rt = 0; rt < 2; ++rt)
#pragma unroll
      for (int rg = 0; rg < 4; ++rg) {
        int row = wv * 32 + rt * 16 + quad * 4 + rg;
        int qp = t0 + row;
        float vals[4];
        float mx = -1e30f;
#pragma unroll
        for (int ct = 0; ct < 4; ++ct) {
          int kp = kv0 + ct * 16 + l15;
          float s = Sa[rt][ct][rg] * 0.08838834764831845f;
          bool ok = (kp <= qp) && (kp + 512 > qp);
          s = ok ? s : -1e30f;
          vals[ct] = s;
          mx = fmaxf(mx, s);
        }
#pragma unroll
        for (int sh = 1; sh < 16; sh <<= 1) mx = fmaxf(mx, __shfl_xor(mx, sh));
        float mold = mrow[rt][rg];
        float mnew = fmaxf(mold, mx);
        float alpha = __expf(mold - mnew);
        float rsum = 0.f;
        float pv_[4];
#pragma unroll
        for (int ct = 0; ct < 4; ++ct) {
          float p = (vals[ct] < -1e29f) ? 0.f : __expf(vals[ct] - mnew);
          pv_[ct] = p; rsum += p;
        }
#pragma unroll
        for (int sh = 1; sh < 16; sh <<= 1) rsum += __shfl_xor(rsum, sh);
        lrow[rt][rg] = lrow[rt][rg] * alpha + rsum;
        mrow[rt][rg] = mnew;
#pragma unroll
        for (int dt = 0; dt < 8; ++dt) Oa[rt][dt][rg] *= alpha;
#pragma unroll
        for (int ct = 0; ct < 4; ++ct) Pls[row * 72 + ct * 16 + l15] = f2bf(pv_[ct]);
      }
    __syncthreads();
#pragma unroll
    for (int ks = 0; ks < 2; ++ks) {
      bf16x8 a0 = *(const bf16x8*)(&Pls[(wv * 32 + l15) * 72 + ks * 32 + quad * 8]);
      bf16x8 a1 = *(const bf16x8*)(&Pls[(wv * 32 + 16 + l15) * 72 + ks * 32 + quad * 8]);
#pragma unroll
      for (int dt = 0; dt < 8; ++dt) {
        bf16x8 bb = *(const bf16x8*)(&VT[(dt * 16 + l15) * 72 + ks * 32 + quad * 8]);
        Oa[0][dt] = __builtin_amdgcn_mfma_f32_16x16x32_bf16(a0, bb, Oa[0][dt], 0, 0, 0);
        Oa[1][dt] = __builtin_amdgcn_mfma_f32_16x16x32_bf16(a1, bb, Oa[1][dt], 0, 0, 0);
      }
    }
  }
#pragma unroll
  for (int rt = 0; rt < 2; ++rt)
#pragma unroll
    for (int rg = 0; rg < 4; ++rg) {
      int row = wv * 32 + rt * 16 + quad * 4 + rg;
      float invl = 1.0f / lrow[rt][rg];
#pragma unroll
      for (int dt = 0; dt < 8; ++dt)
        yin[((size_t)b * T2 + t0 + row) * D2 + h * DH + dt * 16 + l15] = Oa[rt][dt][rg] * invl;
    }
}

// ---------------------------------------------------------------------------
// Kernel 3: slot-memory scan v4.  Same structure as v3, but the barrier no
// longer spins on ACQUIRE loads (each of which emitted buffer_inv, nuking
// the XCD L2 continuously).  Spin is RELAXED (coherence-point load, no cache
// op); exactly ONE acquire fence (buffer_inv) per barrier per block on exit,
// one release (buffer_wbl2) on entry via the ACQ_REL/RELEASE atomics.
// ---------------------------------------------------------------------------
struct ScanArgs {
  const u16* qhb; const u16* khb; const u16* vhb;
  float* yin; float* sk; float* sv; u16* skb; u16* khatb;
  u32* cnt; uint4* entries;
  u32* barcnt; u32* bargen; u32* ready;
  const float* sinit; const float* temp;
};

__device__ __forceinline__ void bh_barrier(u32* cnt, u32* gen) {
  __syncthreads();           // all waves' stores vmcnt-drained to L2
  if (threadIdx.x == 0) {
    u32 g = __hip_atomic_load(gen, __ATOMIC_RELAXED, __HIP_MEMORY_SCOPE_AGENT);
    // release: one buffer_wbl2 flushes this block's dirty lines, then add.
    u32 a = __hip_atomic_fetch_add(cnt, 1u, __ATOMIC_ACQ_REL, __HIP_MEMORY_SCOPE_AGENT);
    if (a == 15u) {
      __hip_atomic_store(cnt, 0u, __ATOMIC_RELAXED, __HIP_MEMORY_SCOPE_AGENT);
      __hip_atomic_store(gen, g + 1u, __ATOMIC_RELEASE, __HIP_MEMORY_SCOPE_AGENT);
    } else {
      // RELAXED spin: no buffer_inv per iteration.
      while (__hip_atomic_load(gen, __ATOMIC_RELAXED, __HIP_MEMORY_SCOPE_AGENT) == g)
        __builtin_amdgcn_s_sleep(2);
      __builtin_amdgcn_fence(__ATOMIC_ACQUIRE, "agent");  // one buffer_inv
    }
  }
  __syncthreads();
}

__device__ __forceinline__ void topk16(const float* rowp, int lane, volatile u64* candw,
                                       float& p_out, u32& idx_out) {
  u32 mono[8];
#pragma unroll
  for (int j = 0; j < 8; ++j) {
    float f = rowp[j * 64 + lane];
    u32 u = __float_as_uint(f);
    mono[j] = ((int)u < 0) ? ~u : (u | 0x80000000u);
  }
  u32 mx = mono[0];
#pragma unroll
  for (int j = 1; j < 8; ++j) mx = max(mx, mono[j]);
  u32 s = mx;
#pragma unroll
  for (int k = 2; k <= 64; k <<= 1) {
#pragma unroll
    for (int j = k >> 1; j > 0; j >>= 1) {
      u32 o = (u32)__shfl_xor((int)s, j);
      bool keep_min = (((lane & k) == 0) == ((lane & j) == 0));
      u32 mn = min(s, o), mxx = max(s, o);
      s = keep_min ? mn : mxx;
    }
  }
  u32 thr = (u32)__shfl((int)s, 48);
  u32 base = 0;
#pragma unroll
  for (int j = 0; j < 8; ++j) {
    bool pred = (mono[j] >= thr);
    u64 mask = __ballot(pred);
    u32 pos = base + (u32)__popcll(mask & ((1ull << lane) - 1ull));
    if (pred && pos < 64u)
      candw[pos] = (((u64)mono[j]) << 32) | (u64)(0xFFFFFFFFu - (u32)(j * 64 + lane));
    base += (u32)__popcll(mask);
  }
  __threadfence_block();
  u32 cntc = base < 64u ? base : 64u;
  u64 key = ((u32)lane < cntc) ? candw[lane] : 0ull;
#pragma unroll
  for (int k = 2; k <= 64; k <<= 1) {
#pragma unroll
    for (int j = k >> 1; j > 0; j >>= 1) {
      u64 o = __shfl_xor(key, j);
      bool keep_min = (((lane & k) == 0) == ((lane & j) == 0));
      u64 mn = key < o ? key : o;
      u64 mxx = key < o ? o : key;
      key = keep_min ? mn : mxx;
    }
  }
  u32 um = (u32)(key >> 32);
  float val = __uint_as_float((um & 0x80000000u) ? (um & 0x7FFFFFFFu) : ~um);
  idx_out = 0xFFFFFFFFu - (u32)(key & 0xFFFFFFFFull);
  float mtop = __shfl(val, 63);
  float e = __expf(val - mtop);
  float ssum = e;
#pragma unroll
  for (int sh = 1; sh < 16; sh <<= 1) ssum += __shfl_xor(ssum, sh);
  p_out = e / ssum;
}

__global__ __launch_bounds__(512, 2) void scan_kernel(ScanArgs A) {
  const int tid = threadIdx.x;
  const int lane = tid & 63, wv = tid >> 6;
  const int quad = lane >> 4, l15 = lane & 15;
  // XCD-affinity mapping: blocks i with i%8==x go to XCD x (heuristic).
  const int xcd = blockIdx.x & 7;
  const int wi = blockIdx.x >> 3;           // 0..31 within XCD
  const int bh = xcd * 2 + (wi >> 4);       // 2 bh per XCD
  const int blk = wi & 15;                  // 16 blocks per bh
  const int b = bh >> 3, h = bh & 7;
  __shared__ u16 khat_ls[8 * 136];
  __shared__ float scores_r[8 * 520];
  __shared__ float scores_w[8 * 520];
  __shared__ u64 cand[8][64];

  const float invtemp = 1.0f / A.temp[0];
  const float sc_r = 0.08838834764831845f * invtemp;

  // ---- init: this block's 32 slots (4 per wave) ----
#pragma unroll 1
  for (int i = 0; i < 4; ++i) {
    int s = blk * 32 + wv * 4 + i;
    float2 v2 = *(const float2*)(A.sinit + (size_t)s * 1024 + h * 128 + lane * 2);
    float ssq = v2.x * v2.x + v2.y * v2.y;
#pragma unroll
    for (int sh = 1; sh < 64; sh <<= 1) ssq += __shfl_xor(ssq, sh);
    float inv = 1.0f / (sqrtf(ssq) + 1e-6f);
    size_t off = ((size_t)bh * KSL + s) * DH + lane * 2;
    *(float2*)(A.sk + off) = make_float2(v2.x * inv, v2.y * inv);
    *(float2*)(A.sv + off) = v2;
    *(u32*)(A.skb + off) = pack2(v2.x * inv, v2.y * inv);
    if (lane == 0)
      __hip_atomic_store(&A.cnt[bh * KSL + s], 0u, __ATOMIC_RELAXED, __HIP_MEMORY_SCOPE_AGENT);
  }
  if (blk == 0 && tid == 0) { A.barcnt[bh] = 0u; A.bargen[bh] = 0u; }
  __syncthreads();
  if (tid == 0) {  // ready-flag gate: RELEASE publish, RELAXED spin, one fence
    __hip_atomic_store(&A.ready[bh * 16 + blk], MAGIC, __ATOMIC_RELEASE, __HIP_MEMORY_SCOPE_AGENT);
    for (int i = 0; i < 16; ++i)
      while (__hip_atomic_load(&A.ready[bh * 16 + i], __ATOMIC_RELAXED, __HIP_MEMORY_SCOPE_AGENT) != MAGIC)
        __builtin_amdgcn_s_sleep(2);
    __builtin_amdgcn_fence(__ATOMIC_ACQUIRE, "agent");
  }
  __syncthreads();

  u32* bcnt = A.barcnt + bh;
  u32* bgen = A.bargen + bh;

#pragma unroll 1
  for (int ci = 0; ci < NCH; ++ci) {
    const int t0base = ci * CH;
    const int c = blk * 8 + wv;          // this wave's chunk-row
    const int trow = t0base + c;
    // ---- A0: k-hat for row c ----
    {
      u32 kraw = *(const u32*)(A.khb + ((size_t)bh * T2 + trow) * DH + lane * 2);
      float k0 = bf2f(kraw & 0xFFFFu), k1 = bf2f(kraw >> 16);
      float ssq = k0 * k0 + k1 * k1;
#pragma unroll
      for (int sh = 1; sh < 64; sh <<= 1) ssq += __shfl_xor(ssq, sh);
      float inv = 1.0f / (sqrtf(ssq) + 1e-6f);
      u32 pk = pack2(k0 * inv, k1 * inv);
      *(u32*)(&khat_ls[wv * 136 + lane * 2]) = pk;
      *(u32*)(A.khatb + ((size_t)bh * CH + c) * DH + lane * 2) = pk;
    }
    __syncthreads();
    // ---- A13: fused scores. A-rows 0-7 = q rows, 8-15 = khat rows. ----
    {
      const u16* qbase = A.qhb + ((size_t)bh * T2 + t0base + blk * 8) * DH;
      const u16* sbase = A.skb + (size_t)bh * KSL * DH;
      f32x4 acc[4];
#pragma unroll
      for (int ct = 0; ct < 4; ++ct) acc[ct] = f32x4{0.f, 0.f, 0.f, 0.f};
#pragma unroll
      for (int ks = 0; ks < 4; ++ks) {
        bf16x8 a;
        if (l15 < 8)
          a = *(const bf16x8*)(qbase + (size_t)l15 * DH + ks * 32 + quad * 8);
        else
          a = *(const bf16x8*)(&khat_ls[(l15 - 8) * 136 + ks * 32 + quad * 8]);
#pragma unroll
        for (int ct = 0; ct < 4; ++ct) {
          bf16x8 bb = *(const bf16x8*)(sbase + (size_t)(wv * 64 + ct * 16 + l15) * DH + ks * 32 + quad * 8);
          acc[ct] = __builtin_amdgcn_mfma_f32_16x16x32_bf16(a, bb, acc[ct], 0, 0, 0);
        }
      }
#pragma unroll
      for (int ct = 0; ct < 4; ++ct)
#pragma unroll
        for (int rg = 0; rg < 4; ++rg) {
          int m = quad * 4 + rg;
          int col = wv * 64 + ct * 16 + l15;
          if (m < 8) scores_r[m * 520 + col] = acc[ct][rg] * sc_r;
          else       scores_w[(m - 8) * 520 + col] = acc[ct][rg];
        }
    }
    __syncthreads();
    // ---- A24: both top-16s; read-gather into yin; write-append entries ----
    {
      float p; u32 sidx;
      topk16(&scores_r[wv * 520], lane, cand[wv], p, sidx);
      float acc0 = 0.f, acc1 = 0.f;
      const float* svb = A.sv + (size_t)bh * KSL * DH;
#pragma unroll
      for (int r = 0; r < 16; ++r) {
        float pr = __shfl(p, 63 - r);
        u32 ir = (u32)__shfl((int)sidx, 63 - r);
        float2 vv = *(const float2*)(svb + (size_t)ir * DH + lane * 2);
        acc0 += pr * vv.x; acc1 += pr * vv.y;
      }
      float* yp = A.yin + ((size_t)b * T2 + trow) * D2 + h * DH + lane * 2;
      yp[0] += acc0; yp[1] += acc1;

      float wp; u32 widx;
      topk16(&scores_w[wv * 520], lane, cand[wv], wp, widx);
      const int r = lane >> 2, g = lane & 3;   // 16 picks x 4 lanes
      float wr = __shfl(wp, 63 - r);
      u32 ir = (u32)__shfl((int)widx, 63 - r);
      const float* kb = A.sk + ((size_t)bh * KSL + ir) * DH + g * 32;
      const u16* vb = A.vhb + ((size_t)bh * T2 + trow) * DH + g * 32;
      float part = 0.f;
#pragma unroll
      for (int u2 = 0; u2 < 4; ++u2) {
        uint4 vvp = *(const uint4*)(vb + u2 * 8);
        float4 k0 = *(const float4*)(kb + u2 * 8);
        float4 k1 = *(const float4*)(kb + u2 * 8 + 4);
        part += bf2f(vvp.x & 0xFFFFu) * k0.x + bf2f(vvp.x >> 16) * k0.y
              + bf2f(vvp.y & 0xFFFFu) * k0.z + bf2f(vvp.y >> 16) * k0.w
              + bf2f(vvp.z & 0xFFFFu) * k1.x + bf2f(vvp.z >> 16) * k1.y
              + bf2f(vvp.w & 0xFFFFu) * k1.z + bf2f(vvp.w >> 16) * k1.w;
      }
      part += __shfl_xor(part, 1);
      part += __shfl_xor(part, 2);
      if (g == 0) {
        u32 pos = atomicAdd(&A.cnt[bh * KSL + ir], 1u);
        A.entries[((size_t)bh * KSL + ir) * 128 + pos] =
            make_uint4((u32)c, __float_as_uint(wr), __float_as_uint(part), 0u);
      }
    }
    bh_barrier(bcnt, bgen);
    // ---- B: each owned slot pulls its updates (batch-8 entry loads) ----
#pragma unroll 1
    for (int i = 0; i < 4; ++i) {
      int s = blk * 32 + wv * 4 + i;
      size_t slotoff = (size_t)bh * KSL + s;
      size_t roff = slotoff * DH + lane * 2;
      u32 n = __hip_atomic_load(&A.cnt[slotoff], __ATOMIC_RELAXED, __HIP_MEMORY_SCOPE_AGENT);
      float2 V = *(const float2*)(A.sv + roff);
      float2 Kr = *(const float2*)(A.sk + roff);
      float dv0 = 0, dv1 = 0, dk0 = 0, dk1 = 0;
      u32 nd = n < 128u ? n : 128u;
      const uint4* ebase = A.entries + slotoff * 128;
#pragma unroll 1
      for (u32 base2 = 0; base2 < nd; base2 += 8) {
        u32 m = nd - base2; if (m > 8u) m = 8u;
        uint4 eb[8];
#pragma unroll
        for (int j = 0; j < 8; ++j) if (j < (int)m) eb[j] = ebase[base2 + j];
        u32 vr[8], hr[8];
#pragma unroll
        for (int j = 0; j < 8; ++j) if (j < (int)m) {
          u32 c2 = eb[j].x;
          vr[j] = *(const u32*)(A.vhb + ((size_t)bh * T2 + t0base + c2) * DH + lane * 2);
          hr[j] = *(const u32*)(A.khatb + ((size_t)bh * CH + c2) * DH + lane * 2);
        }
#pragma unroll
        for (int j = 0; j < 8; ++j) if (j < (int)m) {
          float wpe = __uint_as_float(eb[j].y), pj = __uint_as_float(eb[j].z);
          dv0 += wpe * (bf2f(vr[j] & 0xFFFFu) - pj * Kr.x);
          dv1 += wpe * (bf2f(vr[j] >> 16) - pj * Kr.y);
          dk0 += wpe * (bf2f(hr[j] & 0xFFFFu) - Kr.x);
          dk1 += wpe * (bf2f(hr[j] >> 16) - Kr.y);
        }
      }
      *(float2*)(A.sv + roff) = make_float2(0.99f * V.x + 0.1f * dv0, 0.99f * V.y + 0.1f * dv1);
      if (n > 0u) {
        float u0 = Kr.x + 0.1f * dk0, u1 = Kr.y + 0.1f * dk1;
        float ssq = u0 * u0 + u1 * u1;
#pragma unroll
        for (int sh = 1; sh < 64; sh <<= 1) ssq += __shfl_xor(ssq, sh);
        float inv = 1.0f / (sqrtf(ssq) + 1e-6f);
        u0 *= inv; u1 *= inv;
        *(float2*)(A.sk + roff) = make_float2(u0, u1);
        *(u32*)(A.skb + roff) = pack2(u0, u1);
      }
      if (lane == 0)
        __hip_atomic_store(&A.cnt[slotoff], 0u, __ATOMIC_RELAXED, __HIP_MEMORY_SCOPE_AGENT);
    }
    bh_barrier(bcnt, bgen);
  }
}

// ---------------------------------------------------------------------------
// Kernel 4: output projection (unchanged)
// ---------------------------------------------------------------------------
__global__ __launch_bounds__(256) void out_gemm(
    const float* __restrict__ yin, const float* __restrict__ w,
    const float* __restrict__ bias, float* __restrict__ out) {
  __shared__ u16 As[128 * 72];
  __shared__ u16 Bs[128 * 72];
  const int tid = threadIdx.x;
  const int lane = tid & 63, wv = tid >> 6;
  const int quad = lane >> 4, l15 = lane & 15;
  const int m0 = blockIdx.y * 128, n0 = blockIdx.x * 128;
  const int wr = wv >> 1, wc = wv & 1;
  f32x4 acc[4][4];
#pragma unroll
  for (int i = 0; i < 4; ++i)
#pragma unroll
    for (int j = 0; j < 4; ++j) acc[i][j] = f32x4{0.f, 0.f, 0.f, 0.f};
  const int f4c = tid & 15, r0 = tid >> 4;
  for (int kt = 0; kt < 16; ++kt) {
#pragma unroll
    for (int i = 0; i < 8; ++i) {
      int row = r0 + i * 16;
      float4 a = *(const float4*)(yin + (size_t)(m0 + row) * 1024 + kt * 64 + f4c * 4);
      float4 b = *(const float4*)(w + (size_t)(n0 + row) * 1024 + kt * 64 + f4c * 4);
      *(uint2*)(&As[row * 72 + f4c * 4]) = make_uint2(pack2(a.x, a.y), pack2(a.z, a.w));
      *(uint2*)(&Bs[row * 72 + f4c * 4]) = make_uint2(pack2(b.x, b.y), pack2(b.z, b.w));
    }
    __syncthreads();
#pragma unroll
    for (int ks = 0; ks < 2; ++ks) {
      bf16x8 af[4], bff[4];
#pragma unroll
      for (int rt = 0; rt < 4; ++rt)
        af[rt] = *(const bf16x8*)(&As[(wr * 64 + rt * 16 + l15) * 72 + ks * 32 + quad * 8]);
#pragma unroll
      for (int ct = 0; ct < 4; ++ct)
        bff[ct] = *(const bf16x8*)(&Bs[(wc * 64 + ct * 16 + l15) * 72 + ks * 32 + quad * 8]);
#pragma unroll
      for (int rt = 0; rt < 4; ++rt)
#pragma unroll
        for (int ct = 0; ct < 4; ++ct)
          acc[rt][ct] = __builtin_amdgcn_mfma_f32_16x16x32_bf16(af[rt], bff[ct], acc[rt][ct], 0, 0, 0);
    }
    __syncthreads();
  }
#pragma unroll
  for (int ct = 0; ct < 4; ++ct) {
    int n = n0 + wc * 64 + ct * 16 + l15;
    float bv = bias[n];
#pragma unroll
    for (int rt = 0; rt < 4; ++rt)
#pragma unroll
      for (int rg = 0; rg < 4; ++rg) {
        int m = m0 + wr * 64 + rt * 16 + quad * 4 + rg;
        out[(size_t)m * 1024 + n] = acc[rt][ct][rg] + bv;
      }
  }
}

// ---------------------------------------------------------------------------
extern "C" void kernel_launch(void* const* d_in, const int* in_sizes, int n_in,
                              void* d_out, int out_size, void* d_ws, size_t ws_size,
                              hipStream_t stream) {
  const float* x = (const float*)d_in[0];
  const float* Wqkv = (const float*)d_in[1];
  const float* bqkv = (const float*)d_in[2];
  const float* Wo = (const float*)d_in[3];
  const float* bo = (const float*)d_in[4];
  const float* Sinit = (const float*)d_in[5];
  const float* temp = (const float*)d_in[6];
  float* out = (float*)d_out;

  char* p = (char*)d_ws;
  auto take = [&](size_t bytes) { char* r = p; p += (bytes + 255) & ~(size_t)255; return r; };
  u16* qhb = (u16*)take((size_t)NBH * T2 * DH * 2);
  u16* khb = (u16*)take((size_t)NBH * T2 * DH * 2);
  u16* vhb = (u16*)take((size_t)NBH * T2 * DH * 2);
  float* yin = (float*)take((size_t)B2 * T2 * D2 * 4);
  float* sk = (float*)take((size_t)NBH * KSL * DH * 4);
  float* sv = (float*)take((size_t)NBH * KSL * DH * 4);
  u16* skb = (u16*)take((size_t)NBH * KSL * DH * 2);
  u16* khatb = (u16*)take((size_t)NBH * CH * DH * 2);
  u32* cnt = (u32*)take((size_t)NBH * KSL * 4);
  uint4* entries = (uint4*)take((size_t)NBH * KSL * 128 * 16);
  u32* barcnt = (u32*)take(64 * 4);
  u32* bargen = (u32*)take(64 * 4);
  u32* ready = (u32*)take(NBH * 16 * 4);

  hipLaunchKernelGGL(qkv_gemm, dim3(24, 32), dim3(256), 0, stream, x, Wqkv, bqkv, qhb, khb, vhb);
  hipLaunchKernelGGL(attn_kernel, dim3(16, 16), dim3(256), 0, stream, qhb, khb, vhb, yin);
  ScanArgs sa{qhb, khb, vhb, yin, sk, sv, skb, khatb, cnt, entries, barcnt, bargen, ready, Sinit, temp};
  hipLaunchKernelGGL(scan_kernel, dim3(256), dim3(512), 0, stream, sa);
  hipLaunchKernelGGL(out_gemm, dim3(8, 32), dim3(256), 0, stream, yin, Wo, bo, out);
}